// Round 13
// baseline (7269.319 us; speedup 1.0000x reference)
//
#include <hip/hip_runtime.h>
#include <hip/hip_bf16.h>

// L=512, B=64, D=H=512, 3H=1536.
// MEGA-KERNEL (single dispatch), 512 blocks x 256 threads, all co-resident
// (launch_bounds(256,2) + 72KB LDS -> exactly 2 blocks/CU = 512 slots):
//   blocks 0..63   : GRU recurrence (r8-proven agent-scope sync, 8 groups x 8
//                    blocks x 4 waves, W_hh register-resident), gated on
//                    gi_done[t/64] chunk counters (8 coarse waits).
//   blocks 64..511 : front pipeline, work-stealing by stride:
//                    S1 Qt tiles -> S2 Pt tiles (t-ordered) -> S3 att items
//                    (t-chunked, needs all Qt + Pt chunk) -> S4 Gi tiles
//                    (t-chunked, needs att chunk).
// All intermediates written with sc1 (MALL); Gi overlays Pt chunk-exactly
// (both 2048 B/row) and is read by rec via sc1 loads (no stale-L2 hazard).
// Dependency graph is one-way (front->front earlier stages, rec->front):
// every poll target is reached unconditionally -> deadlock-free.

typedef float f32x4 __attribute__((ext_vector_type(4)));
typedef short s16x8 __attribute__((ext_vector_type(8)));
typedef short s16x4 __attribute__((ext_vector_type(4)));

#define NF   448
#define NREC 64

#define K_QT  0
#define K_PT  8
#define K_ATT 16
#define K_GI  24
#define K_BAR 64
#define CTRL_WORDS (64 + 4096)

static __device__ __forceinline__ float rcp_fast(float x) { return __builtin_amdgcn_rcpf(x); }
static __device__ __forceinline__ float tanh_fast(float x) {
    float e = __expf(2.0f * x);
    return 1.0f - 2.0f * rcp_fast(e + 1.0f);
}
static __device__ __forceinline__ float sigmoid_fast(float x) {
    return rcp_fast(1.0f + __expf(-x));
}
static __device__ __forceinline__ unsigned short f2bf(float x) {
    union { float f; unsigned u; } v; v.f = x;
    unsigned r = v.u + 0x7FFFu + ((v.u >> 16) & 1u);
    return (unsigned short)(r >> 16);
}
static __device__ __forceinline__ float bf2f(unsigned short b) {
    union { unsigned u; float f; } v; v.u = ((unsigned)b) << 16;
    return v.f;
}
static __device__ __forceinline__ s16x8 pack8(f32x4 a, f32x4 b) {
    s16x8 r;
    r[0] = (short)f2bf(a[0]); r[1] = (short)f2bf(a[1]);
    r[2] = (short)f2bf(a[2]); r[3] = (short)f2bf(a[3]);
    r[4] = (short)f2bf(b[0]); r[5] = (short)f2bf(b[1]);
    r[6] = (short)f2bf(b[2]); r[7] = (short)f2bf(b[3]);
    return r;
}
static __device__ __forceinline__ void split8(f32x4 a, f32x4 b, s16x8* hi, s16x8* lo) {
    s16x8 h, l;
#pragma unroll
    for (int e = 0; e < 4; e++) {
        unsigned short hh = f2bf(a[e]); h[e] = (short)hh;
        l[e] = (short)f2bf(a[e] - bf2f(hh));
    }
#pragma unroll
    for (int e = 0; e < 4; e++) {
        unsigned short hh = f2bf(b[e]); h[4 + e] = (short)hh;
        l[4 + e] = (short)f2bf(b[e] - bf2f(hh));
    }
    *hi = h; *lo = l;
}
static __device__ __forceinline__ f32x4 mfma16(s16x8 a, s16x8 b, f32x4 c) {
    return __builtin_amdgcn_mfma_f32_16x16x32_bf16(a, b, c, 0, 0, 0);
}

// agent-scope (sc1/MALL) primitives — r2-proven
static __device__ __forceinline__ unsigned ld_agent(const unsigned* p) {
    return __hip_atomic_load(p, __ATOMIC_RELAXED, __HIP_MEMORY_SCOPE_AGENT);
}
static __device__ __forceinline__ void add_agent(unsigned* p, unsigned v) {
    __hip_atomic_fetch_add(p, v, __ATOMIC_RELAXED, __HIP_MEMORY_SCOPE_AGENT);
}
static __device__ __forceinline__ void st_agent(unsigned* p, unsigned v) {
    __hip_atomic_store(p, v, __ATOMIC_RELAXED, __HIP_MEMORY_SCOPE_AGENT);
}
static __device__ __forceinline__ void poll_agent_ge(const unsigned* p, unsigned tgt) {
    while (ld_agent(p) < tgt) __builtin_amdgcn_s_sleep(4);
}
static __device__ __forceinline__ void vm_drain() {
    asm volatile("s_waitcnt vmcnt(0)" ::: "memory");
}
// sc1 store helpers (write-through to MALL)
static __device__ __forceinline__ void st_f32_sc1(float* p, float v) {
    asm volatile("global_store_dword %0, %1, off sc1" :: "v"(p), "v"(v) : "memory");
}
static __device__ __forceinline__ void st_u16_sc1(unsigned short* p, unsigned v) {
    asm volatile("global_store_short %0, %1, off sc1" :: "v"(p), "v"(v) : "memory");
}
static __device__ __forceinline__ void st8_sc1(void* p, s16x4 v) {
    asm volatile("global_store_dwordx2 %0, %1, off sc1" :: "v"(p), "v"(v) : "memory");
}
// three 8B sc1 loads, one wait (rec Gi prefetch)
static __device__ __forceinline__ void ld_gi_sc1(const void* p0, const void* p1, const void* p2,
                                                 s16x4* a, s16x4* b, s16x4* c) {
    asm volatile("global_load_dwordx2 %0, %3, off sc1\n\t"
                 "global_load_dwordx2 %1, %4, off sc1\n\t"
                 "global_load_dwordx2 %2, %5, off sc1\n\t"
                 "s_waitcnt vmcnt(0)"
                 : "=v"(*a), "=v"(*b), "=v"(*c)
                 : "v"(p0), "v"(p1), "v"(p2) : "memory");
}

struct SharedMem {
    union {
        struct { unsigned short Al[128 * 72 * 2]; unsigned short Wl[128 * 72 * 2]; } g;
        struct { float sbuf[8][513]; float qst[8][640]; float zinv[8]; } a;
    };
};

// ---------------------------------------------------------------------------
// GEMM tile (device fn). OUTMODE: 0 = f32 sc1 out; 2 = Gi split (RZ/N) bf16 sc1.
// ---------------------------------------------------------------------------
template<int SPLIT, int TANH, int BIAS, int AIN, int OUTMODE>
static __device__ __forceinline__
void gemm_tile(int bm, int bn, const void* Ap, const float* Wp,
               const float* bias, void* outp, void* outp2, int N, SharedMem* sm)
{
    const int tid = threadIdx.x;
    const int w = tid >> 6, lane = tid & 63;
    const int l15 = lane & 15, l4 = lane >> 4;
    unsigned short* Al = sm->g.Al;
    unsigned short* Wl = sm->g.Wl;
    const int LOFS = 128 * 72;

    f32x4 acc[4][4];
#pragma unroll
    for (int i = 0; i < 4; i++)
#pragma unroll
        for (int j = 0; j < 4; j++) acc[i][j] = (f32x4){0.f, 0.f, 0.f, 0.f};

    const int srow = tid >> 1, shalf = tid & 1;
    const float* Asrc = (const float*)Ap + (size_t)(bm * 128 + srow) * 512 + shalf * 32;
    const unsigned short* Asrcb = (const unsigned short*)Ap + (size_t)(bm * 128 + srow) * 512 + shalf * 32;
    const float* Wsrc = Wp + (size_t)(bn * 128 + srow) * 512 + shalf * 32;
    unsigned short* Adst = Al + srow * 72 + shalf * 32;
    unsigned short* Wdst = Wl + srow * 72 + shalf * 32;

    for (int k0 = 0; k0 < 512; k0 += 64) {
        __syncthreads();
        if (AIN) {
#pragma unroll
            for (int j = 0; j < 4; j++)
                *(s16x8*)(Adst + j * 8) = *(const s16x8*)(Asrcb + k0 + j * 8);
        } else if (SPLIT) {
#pragma unroll
            for (int j = 0; j < 4; j++) {
                f32x4 x = *(const f32x4*)(Asrc + k0 + j * 8);
                f32x4 y = *(const f32x4*)(Asrc + k0 + j * 8 + 4);
                s16x8 hi, lo; split8(x, y, &hi, &lo);
                *(s16x8*)(Adst + j * 8) = hi;
                *(s16x8*)(Adst + LOFS + j * 8) = lo;
            }
        } else {
#pragma unroll
            for (int j = 0; j < 4; j++) {
                f32x4 x = *(const f32x4*)(Asrc + k0 + j * 8);
                f32x4 y = *(const f32x4*)(Asrc + k0 + j * 8 + 4);
                *(s16x8*)(Adst + j * 8) = pack8(x, y);
            }
        }
        if (SPLIT) {
#pragma unroll
            for (int j = 0; j < 4; j++) {
                f32x4 x = *(const f32x4*)(Wsrc + k0 + j * 8);
                f32x4 y = *(const f32x4*)(Wsrc + k0 + j * 8 + 4);
                s16x8 hi, lo; split8(x, y, &hi, &lo);
                *(s16x8*)(Wdst + j * 8) = hi;
                *(s16x8*)(Wdst + LOFS + j * 8) = lo;
            }
        } else {
#pragma unroll
            for (int j = 0; j < 4; j++) {
                f32x4 x = *(const f32x4*)(Wsrc + k0 + j * 8);
                f32x4 y = *(const f32x4*)(Wsrc + k0 + j * 8 + 4);
                *(s16x8*)(Wdst + j * 8) = pack8(x, y);
            }
        }
        __syncthreads();

#pragma unroll
        for (int kt = 0; kt < 2; kt++) {
            s16x8 afh[4], bfh[4];
#pragma unroll
            for (int mb = 0; mb < 4; mb++)
                afh[mb] = *(const s16x8*)(Al + ((w & 1) * 64 + mb * 16 + l15) * 72 + kt * 32 + l4 * 8);
#pragma unroll
            for (int nb = 0; nb < 4; nb++)
                bfh[nb] = *(const s16x8*)(Wl + ((w >> 1) * 64 + nb * 16 + l15) * 72 + kt * 32 + l4 * 8);
            if (SPLIT) {
                s16x8 afl[4], bfl[4];
#pragma unroll
                for (int mb = 0; mb < 4; mb++)
                    afl[mb] = *(const s16x8*)(Al + LOFS + ((w & 1) * 64 + mb * 16 + l15) * 72 + kt * 32 + l4 * 8);
#pragma unroll
                for (int nb = 0; nb < 4; nb++)
                    bfl[nb] = *(const s16x8*)(Wl + LOFS + ((w >> 1) * 64 + nb * 16 + l15) * 72 + kt * 32 + l4 * 8);
#pragma unroll
                for (int mb = 0; mb < 4; mb++)
#pragma unroll
                    for (int nb = 0; nb < 4; nb++) {
                        acc[mb][nb] = mfma16(afh[mb], bfh[nb], acc[mb][nb]);
                        acc[mb][nb] = mfma16(afh[mb], bfl[nb], acc[mb][nb]);
                        acc[mb][nb] = mfma16(afl[mb], bfh[nb], acc[mb][nb]);
                    }
            } else {
#pragma unroll
                for (int mb = 0; mb < 4; mb++)
#pragma unroll
                    for (int nb = 0; nb < 4; nb++)
                        acc[mb][nb] = mfma16(afh[mb], bfh[nb], acc[mb][nb]);
            }
        }
    }

    const int m0 = bm * 128 + (w & 1) * 64;
    const int n0 = bn * 128 + (w >> 1) * 64;
#pragma unroll
    for (int nb = 0; nb < 4; nb++) {
        float bv = 0.0f;
        const int n = n0 + nb * 16 + l15;
        if (BIAS) bv = bias[n];
#pragma unroll
        for (int mb = 0; mb < 4; mb++) {
#pragma unroll
            for (int i = 0; i < 4; i++) {
                const int m = m0 + mb * 16 + l4 * 4 + i;
                float vv = acc[mb][nb][i];
                if (BIAS) vv += bv;
                if (TANH) vv = tanh_fast(vv);
                if (OUTMODE == 0) {
                    st_f32_sc1((float*)outp + (size_t)m * N + n, vv);
                } else {
                    unsigned hv = f2bf(vv);
                    if (n < 1024) st_u16_sc1((unsigned short*)outp  + (size_t)m * 1024 + n, hv);
                    else          st_u16_sc1((unsigned short*)outp2 + (size_t)m * 512 + (n - 1024), hv);
                }
            }
        }
    }
}

// ---------------------------------------------------------------------------
// Attention item (256 threads): t-tile of 8 (tblk 0..63) x one b.
// ---------------------------------------------------------------------------
static __device__ __forceinline__
void att_item(int tblk, int b, const float* Pt, const float* Qt,
              const float* Vv, const float* vin, unsigned short* cbuf, SharedMem* sm)
{
    const int tid = threadIdx.x;
    const int w = tid >> 6, lane = tid & 63;
    const int t_in = lane >> 5, sl = lane & 31;
    const int t_loc = w * 2 + t_in;          // 0..7
    const int tg = tblk * 8 + t_loc;

    float (*sbuf)[513] = sm->a.sbuf;
    float (*qst)[640]  = sm->a.qst;
    float* zinv = sm->a.zinv;

    float Pa[16], Vb[16], VbA[16];
    {
        const float* pp = Pt + ((size_t)tg * 64 + b) * 512 + sl * 16;
        const float* vb = Vv + (size_t)b * 512 + sl * 16;
#pragma unroll
        for (int j = 0; j < 4; j++) {
            f32x4 x = *(const f32x4*)(pp + j * 4);
            f32x4 y = *(const f32x4*)(vb + j * 4);
#pragma unroll
            for (int e = 0; e < 4; e++) { Pa[j * 4 + e] = x[e]; Vb[j * 4 + e] = y[e]; }
        }
#pragma unroll
        for (int e = 0; e < 16; e++) VbA[e] = Vb[e] * Pa[e];
    }

    // Phase A: logits
    for (int l0 = 0; l0 < 512; l0 += 8) {
        __syncthreads();
        {
            const int cb0 = (tid & 63) * 8;
            const int f0 = cb0 + 4 * (cb0 >> 4);
            const int r0 = tid >> 6;                    // 0..3
            const float* s1 = Qt + ((size_t)(l0 + r0) * 64 + b) * 512 + cb0;
            const float* s2 = Qt + ((size_t)(l0 + r0 + 4) * 64 + b) * 512 + cb0;
            *(f32x4*)(&qst[r0][f0])         = *(const f32x4*)(s1);
            *(f32x4*)(&qst[r0][f0 + 4])     = *(const f32x4*)(s1 + 4);
            *(f32x4*)(&qst[r0 + 4][f0])     = *(const f32x4*)(s2);
            *(f32x4*)(&qst[r0 + 4][f0 + 4]) = *(const f32x4*)(s2 + 4);
        }
        __syncthreads();
        for (int l = 0; l < 8; l++) {
            const float* qrow = &qst[l][sl * 20];
            float a0 = 0.f, a1 = 0.f, a2 = 0.f, a3 = 0.f;
#pragma unroll
            for (int j = 0; j < 4; j++) {
                f32x4 q = *(const f32x4*)(qrow + j * 4);
                {
                    float d = fmaf(Pa[4 * j + 0], q[0], 1.0f);
                    a0 = fmaf(fmaf(Vb[4 * j + 0], q[0], VbA[4 * j + 0]), rcp_fast(d), a0);
                }
                {
                    float d = fmaf(Pa[4 * j + 1], q[1], 1.0f);
                    a1 = fmaf(fmaf(Vb[4 * j + 1], q[1], VbA[4 * j + 1]), rcp_fast(d), a1);
                }
                {
                    float d = fmaf(Pa[4 * j + 2], q[2], 1.0f);
                    a2 = fmaf(fmaf(Vb[4 * j + 2], q[2], VbA[4 * j + 2]), rcp_fast(d), a2);
                }
                {
                    float d = fmaf(Pa[4 * j + 3], q[3], 1.0f);
                    a3 = fmaf(fmaf(Vb[4 * j + 3], q[3], VbA[4 * j + 3]), rcp_fast(d), a3);
                }
            }
            float accp = (a0 + a1) + (a2 + a3);
#pragma unroll
            for (int m = 1; m < 32; m <<= 1) accp += __shfl_xor(accp, m, 64);
            if (sl == 0) sbuf[t_loc][l0 + l] = accp;
        }
    }
    __syncthreads();

    // Phase B: softmax
    {
        const int tr = tid >> 5;       // 0..7
        const int i = tid & 31;
        float m = -1e30f;
        for (int l = i; l < 512; l += 32) m = fmaxf(m, sbuf[tr][l]);
#pragma unroll
        for (int mm = 1; mm < 32; mm <<= 1) m = fmaxf(m, __shfl_xor(m, mm, 64));
        float z = 0.0f;
        for (int l = i; l < 512; l += 32) {
            float e = __expf(sbuf[tr][l] - m);
            sbuf[tr][l] = e;
            z += e;
        }
#pragma unroll
        for (int mm = 1; mm < 32; mm <<= 1) z += __shfl_xor(z, mm, 64);
        if (i == 0) zinv[tr] = rcp_fast(z);
    }
    __syncthreads();

    // Phase C: c
    float ca[16];
#pragma unroll
    for (int j = 0; j < 16; j++) ca[j] = 0.0f;

    for (int l0 = 0; l0 < 512; l0 += 8) {
        __syncthreads();
        {
            const int cb0 = (tid & 63) * 8;
            const int f0 = cb0 + 4 * (cb0 >> 4);
            const int r0 = tid >> 6;
            const float* s1 = vin + ((size_t)(l0 + r0) * 64 + b) * 512 + cb0;
            const float* s2 = vin + ((size_t)(l0 + r0 + 4) * 64 + b) * 512 + cb0;
            *(f32x4*)(&qst[r0][f0])         = *(const f32x4*)(s1);
            *(f32x4*)(&qst[r0][f0 + 4])     = *(const f32x4*)(s1 + 4);
            *(f32x4*)(&qst[r0 + 4][f0])     = *(const f32x4*)(s2);
            *(f32x4*)(&qst[r0 + 4][f0 + 4]) = *(const f32x4*)(s2 + 4);
        }
        __syncthreads();
        for (int l = 0; l < 8; l++) {
            const float a = sbuf[t_loc][l0 + l];
            const float* vrow = &qst[l][sl * 20];
#pragma unroll
            for (int j = 0; j < 4; j++) {
                f32x4 x = *(const f32x4*)(vrow + j * 4);
                ca[4 * j + 0] = fmaf(a, x[0], ca[4 * j + 0]);
                ca[4 * j + 1] = fmaf(a, x[1], ca[4 * j + 1]);
                ca[4 * j + 2] = fmaf(a, x[2], ca[4 * j + 2]);
                ca[4 * j + 3] = fmaf(a, x[3], ca[4 * j + 3]);
            }
        }
    }
    const float zi = zinv[t_loc];
    unsigned short* co = cbuf + ((size_t)tg * 64 + b) * 512 + sl * 16;
#pragma unroll
    for (int j = 0; j < 4; j++) {
        s16x4 o;
        o[0] = (short)f2bf(ca[4 * j + 0] * zi);
        o[1] = (short)f2bf(ca[4 * j + 1] * zi);
        o[2] = (short)f2bf(ca[4 * j + 2] * zi);
        o[3] = (short)f2bf(ca[4 * j + 3] * zi);
        st8_sc1(co + j * 4, o);
    }
}

// ---------------------------------------------------------------------------
// Mega-kernel
// ---------------------------------------------------------------------------
__global__ __launch_bounds__(256, 2)
void mega_k(const float* __restrict__ v, const float* __restrict__ h0,
            const float* __restrict__ Vv,
            const float* __restrict__ Wp, const float* __restrict__ Wp_,
            const float* __restrict__ Wih, const float* __restrict__ Whh,
            const float* __restrict__ bih, const float* __restrict__ bhh,
            float* Qt, float* Pt, unsigned short* cb,
            unsigned short* GiN, unsigned int* hb32,
            unsigned int* ctrl, float* hs)
{
    __shared__ SharedMem sm;
    const int bid = blockIdx.x;
    const int tid = threadIdx.x;

    if (bid >= NREC) {
        // ================= FRONT =================
        const int f = bid - NREC;
        // S1: Qt
        for (int i = f; i < 1024; i += NF) {
            gemm_tile<1, 1, 0, 0, 0>(i >> 2, i & 3, v, Wp_, nullptr, Qt, nullptr, 512, &sm);
            vm_drain(); __syncthreads();
            if (tid == 0) add_agent(ctrl + K_QT, 1u);
        }
        // S2: Pt (t-ordered)
        for (int i = f; i < 1024; i += NF) {
            gemm_tile<1, 1, 0, 0, 0>(i >> 2, i & 3, v, Wp, nullptr, Pt, nullptr, 512, &sm);
            vm_drain(); __syncthreads();
            if (tid == 0) add_agent(ctrl + K_PT + ((i >> 2) >> 5), 1u);
        }
        // S3: attention (needs all Qt + Pt chunk)
        if (tid == 0) poll_agent_ge(ctrl + K_QT, 1024u);
        __syncthreads();
        for (int i = f; i < 4096; i += NF) {
            const int tb = i >> 6, b = i & 63, c = tb >> 3;
            if (tid == 0) poll_agent_ge(ctrl + K_PT + c, 128u);
            __syncthreads();
            att_item(tb, b, Pt, Qt, Vv, v, cb, &sm);
            vm_drain(); __syncthreads();
            if (tid == 0) add_agent(ctrl + K_ATT + c, 1u);
        }
        // S4: Gi (needs att chunk). GiRZ overlays Pt (chunk-exact, 2048B/row).
        unsigned short* GiRZ = (unsigned short*)Pt;
        for (int i = f; i < 3072; i += NF) {
            const int bm = i / 12, bn = i - bm * 12, c = bm >> 5;
            if (tid == 0) poll_agent_ge(ctrl + K_ATT + c, 512u);
            __syncthreads();
            gemm_tile<0, 0, 1, 1, 2>(bm, bn, cb, Wih, bih, GiRZ, GiN, 1536, &sm);
            vm_drain(); __syncthreads();
            if (tid == 0) add_agent(ctrl + K_GI + c, 1u);
        }
        return;
    }

    // ================= RECURRENCE (r8-proven agent path) =================
    const unsigned short* GiRZ = (const unsigned short*)Pt;
    const int g = bid >> 3;          // group: 8 b's
    const int sub = bid & 7;         // j-slice
    const int w = tid >> 6;
    const int lane = tid & 63;
    const int l15 = lane & 15, l4 = lane >> 4;
    const int b  = g * 8 + (l15 & 7);
    const int jb = sub * 64 + w * 16;
    const int jrow = l4 * 4;
    const bool writer = (l15 < 8);

    s16x8 wf[3][16];
#pragma unroll
    for (int gg = 0; gg < 3; gg++) {
        const float* wr = Whh + (size_t)(gg * 512 + jb + l15) * 512 + l4 * 8;
#pragma unroll
        for (int c = 0; c < 16; c++) {
            f32x4 x = *(const f32x4*)(wr + c * 32);
            f32x4 y = *(const f32x4*)(wr + c * 32 + 4);
            wf[gg][c] = pack8(x, y);
        }
    }

    float bh_r[4], bh_z[4], bh_n[4];
#pragma unroll
    for (int i = 0; i < 4; i++) {
        bh_r[i] = bhh[jb + jrow + i];
        bh_z[i] = bhh[512 + jb + jrow + i];
        bh_n[i] = bhh[1024 + jb + jrow + i];
    }
    float hp[4];
#pragma unroll
    for (int i = 0; i < 4; i++) hp[i] = h0[(size_t)b * 512 + jb + jrow + i];

    unsigned* barA = ctrl + K_BAR + g * 512;

    // gate on Gi chunk 0, then load Gi[0] via sc1 (bypass caches)
    if (tid == 0) poll_agent_ge(ctrl + K_GI + 0, 384u);
    __syncthreads();
    s16x4 g0, g1, g2;
    ld_gi_sc1(GiRZ + (size_t)b * 1024 + jb + jrow,
              GiRZ + (size_t)b * 1024 + 512 + jb + jrow,
              GiN  + (size_t)b * 512 + jb + jrow, &g0, &g1, &g2);

    for (int t = 0; t < 512; t++) {
        s16x8 hfrag[16];
        if (t == 0) {
            const float* hr = h0 + (size_t)b * 512 + l4 * 8;
#pragma unroll
            for (int c = 0; c < 16; c++) {
                f32x4 x = *(const f32x4*)(hr + c * 32);
                f32x4 y = *(const f32x4*)(hr + c * 32 + 4);
                hfrag[c] = pack8(x, y);
            }
        } else {
            const unsigned int* src = hb32 + (t & 1) * 16384 + b * 256 + l4 * 4;
#pragma unroll
            for (int c = 0; c < 16; c++) {
                union { unsigned int u[4]; s16x8 vv; } cv;
#pragma unroll
                for (int q = 0; q < 4; q++)
                    cv.u[q] = ld_agent(src + c * 16 + q);
                hfrag[c] = cv.vv;
            }
        }

        f32x4 acc0 = {0.f, 0.f, 0.f, 0.f};
        f32x4 acc1 = {0.f, 0.f, 0.f, 0.f};
        f32x4 acc2 = {0.f, 0.f, 0.f, 0.f};
#pragma unroll
        for (int c = 0; c < 16; c++) {
            acc0 = mfma16(wf[0][c], hfrag[c], acc0);
            acc1 = mfma16(wf[1][c], hfrag[c], acc1);
            acc2 = mfma16(wf[2][c], hfrag[c], acc2);
        }

#pragma unroll
        for (int i = 0; i < 4; i++) {
            float rr = sigmoid_fast(bf2f((unsigned short)g0[i]) + acc0[i] + bh_r[i]);
            float zz = sigmoid_fast(bf2f((unsigned short)g1[i]) + acc1[i] + bh_z[i]);
            float nn = tanh_fast(bf2f((unsigned short)g2[i]) + rr * (acc2[i] + bh_n[i]));
            hp[i] = fmaf(zz, hp[i] - nn, nn);
        }

        float* hso = hs + ((size_t)t * 64 + b) * 512 + jb + jrow;
        f32x4 hv = {hp[0], hp[1], hp[2], hp[3]};

        if (t < 511) {
            const unsigned p0 = (unsigned)f2bf(hp[0]) | ((unsigned)f2bf(hp[1]) << 16);
            const unsigned p1 = (unsigned)f2bf(hp[2]) | ((unsigned)f2bf(hp[3]) << 16);
            unsigned int* dst = hb32 + ((t + 1) & 1) * 16384 + b * 256 + ((jb + jrow) >> 1);
            if (writer) { st_agent(dst, p0); st_agent(dst + 1, p1); }
            vm_drain();
            __syncthreads();                        // all waves' h stores at MALL
            if (tid == 0) add_agent(barA + t, 1u);
            if (writer) *(f32x4*)hso = hv;          // output store (plain)

            // Gi chunk gate (coarse, 8x total) + Gi[t+1] prefetch (sc1)
            if (((t + 1) & 63) == 0) {
                if (tid == 0) poll_agent_ge(ctrl + K_GI + ((t + 1) >> 6), 384u);
                __syncthreads();
            }
            {
                const size_t r = (size_t)(t + 1) * 64 + b;
                ld_gi_sc1(GiRZ + r * 1024 + jb + jrow,
                          GiRZ + r * 1024 + 512 + jb + jrow,
                          GiN  + r * 512 + jb + jrow, &g0, &g1, &g2);
            }
            // wait peers
            for (;;) {
                unsigned vbar = ld_agent(barA + t);
                if (vbar >= 8u) break;
                __builtin_amdgcn_s_sleep(1);
            }
        } else {
            if (writer) *(f32x4*)hso = hv;
        }
    }
}

// ---------------------------------------------------------------------------
// ws layout (bytes) — 192.2 MiB total (r1-proven footprint):
//   Qt   : [0, 64Mi)          f32  (sc1-written, plain-read)
//   Pt   : [64Mi, 128Mi)      f32; later overlaid chunk-exactly by GiRZ
//          (bf16 rows of 1024 = 2048B/row, same as Pt's 2048B/row)
//   cb   : [128Mi, 160Mi)     bf16
//   GiN  : [160Mi, 192Mi)     bf16 (gi_n)
//   hb32 : [192Mi, +128Ki)    u32 h exchange (agent ops)
//   ctrl : [192Mi+128Ki, +~17KB) counters + barA (memset per launch)
// ---------------------------------------------------------------------------
extern "C" void kernel_launch(void* const* d_in, const int* in_sizes, int n_in,
                              void* d_out, int out_size, void* d_ws, size_t ws_size,
                              hipStream_t stream)
{
    (void)in_sizes; (void)n_in; (void)out_size; (void)ws_size;
    const float* v   = (const float*)d_in[0];
    const float* h0  = (const float*)d_in[1];
    const float* Vv  = (const float*)d_in[2];
    const float* Wp  = (const float*)d_in[3];
    const float* Wp_ = (const float*)d_in[4];
    const float* Wih = (const float*)d_in[5];
    const float* Whh = (const float*)d_in[6];
    const float* bih = (const float*)d_in[7];
    const float* bhh = (const float*)d_in[8];
    float* hs = (float*)d_out;

    char* ws = (char*)d_ws;
    float* Qt = (float*)(ws);
    float* Pt = (float*)(ws + 67108864ULL);
    unsigned short* cb  = (unsigned short*)(ws + 134217728ULL);
    unsigned short* GiN = (unsigned short*)(ws + 167772160ULL);
    unsigned int*   hb32 = (unsigned int*)(ws + 201326592ULL);
    unsigned int*   ctrl = (unsigned int*)(ws + 201326592ULL + 131072ULL);

    hipMemsetAsync(ctrl, 0, CTRL_WORDS * sizeof(unsigned int), stream);

    mega_k<<<dim3(NREC + NF), 256, 0, stream>>>(v, h0, Vv, Wp, Wp_, Wih, Whh, bih, bhh,
                                                Qt, Pt, cb, GiN, hb32, ctrl, hs);
}

// Round 14
// 3941.814 us; speedup vs baseline: 1.8442x; 1.8442x over previous
//
#include <hip/hip_runtime.h>
#include <hip/hip_bf16.h>

// L=512, B=64, D=H=512, 3H=1536.
//  pq_k: fused Ep = exp(2·v@Wp^T), Eq = exp(2·v@Wp_^T)  (split-bf16 3-pass MFMA,
//        A-tile staged once, W tiles sequential in same LDS)
//  att_k: logits via exp form  Vb·tanh(p+q) = Vb − 2Vb·rcp(1+Ep·Eq)
//        (2 VALU + 1 rcp per element, ΣVb hoisted), softmax, c = a·v (c bf16)
//  gemm_k<AIN,BIAS,OUTBF16>: Gi = c@W_ih^T + b_ih
//  rec_k v11: r8's MEASURED path only (r11 beacon proved the "XCD fast path"
//        never executed). 64 blocks, 8 groups x 8 blocks x 4 waves, W_hh
//        register-resident, agent-scope (sc1) h exchange + per-block flag +
//        poll. h loads widened to dwordx4 sc1.

typedef float f32x4 __attribute__((ext_vector_type(4)));
typedef short s16x8 __attribute__((ext_vector_type(8)));
typedef short s16x4 __attribute__((ext_vector_type(4)));
typedef unsigned int u32x2 __attribute__((ext_vector_type(2)));

static __device__ __forceinline__ float rcp_fast(float x) { return __builtin_amdgcn_rcpf(x); }
static __device__ __forceinline__ float tanh_fast(float x) {
    float e = __expf(2.0f * x);
    return 1.0f - 2.0f * rcp_fast(e + 1.0f);
}
static __device__ __forceinline__ float sigmoid_fast(float x) {
    return rcp_fast(1.0f + __expf(-x));
}
static __device__ __forceinline__ unsigned short f2bf(float x) {
    union { float f; unsigned u; } v; v.f = x;
    unsigned r = v.u + 0x7FFFu + ((v.u >> 16) & 1u);
    return (unsigned short)(r >> 16);
}
static __device__ __forceinline__ float bf2f(unsigned short b) {
    union { unsigned u; float f; } v; v.u = ((unsigned)b) << 16;
    return v.f;
}
static __device__ __forceinline__ s16x8 pack8(f32x4 a, f32x4 b) {
    s16x8 r;
    r[0] = (short)f2bf(a[0]); r[1] = (short)f2bf(a[1]);
    r[2] = (short)f2bf(a[2]); r[3] = (short)f2bf(a[3]);
    r[4] = (short)f2bf(b[0]); r[5] = (short)f2bf(b[1]);
    r[6] = (short)f2bf(b[2]); r[7] = (short)f2bf(b[3]);
    return r;
}
static __device__ __forceinline__ void split8(f32x4 a, f32x4 b, s16x8* hi, s16x8* lo) {
    s16x8 h, l;
#pragma unroll
    for (int e = 0; e < 4; e++) {
        unsigned short hh = f2bf(a[e]); h[e] = (short)hh;
        l[e] = (short)f2bf(a[e] - bf2f(hh));
    }
#pragma unroll
    for (int e = 0; e < 4; e++) {
        unsigned short hh = f2bf(b[e]); h[4 + e] = (short)hh;
        l[4 + e] = (short)f2bf(b[e] - bf2f(hh));
    }
    *hi = h; *lo = l;
}
static __device__ __forceinline__ f32x4 mfma16(s16x8 a, s16x8 b, f32x4 c) {
    return __builtin_amdgcn_mfma_f32_16x16x32_bf16(a, b, c, 0, 0, 0);
}
static __device__ __forceinline__ unsigned ld_agent(const unsigned* p) {
    return __hip_atomic_load(p, __ATOMIC_RELAXED, __HIP_MEMORY_SCOPE_AGENT);
}
static __device__ __forceinline__ void add_agent(unsigned* p, unsigned v) {
    __hip_atomic_fetch_add(p, v, __ATOMIC_RELAXED, __HIP_MEMORY_SCOPE_AGENT);
}
static __device__ __forceinline__ void vm_drain() {
    asm volatile("s_waitcnt vmcnt(0)" ::: "memory");
}

// ---------------------------------------------------------------------------
// Fused P/Q GEMM: Ep/Eq = exp(2·(v @ W^T)), split-bf16 3-pass.
// 128x128 tile, BK=64, 4 waves. A staged ONCE per k0; W1 then W2 share Wl.
// ---------------------------------------------------------------------------
__global__ __launch_bounds__(256, 2)
void pq_k(const float* __restrict__ v, const float* __restrict__ Wp,
          const float* __restrict__ Wp_, float* __restrict__ Ep,
          float* __restrict__ Eq)
{
    const int bm = blockIdx.x, bn = blockIdx.y;
    const int tid = threadIdx.x;
    const int w = tid >> 6, lane = tid & 63;
    const int l15 = lane & 15, l4 = lane >> 4;

    __shared__ unsigned short Al[128 * 72 * 2];
    __shared__ unsigned short Wl[128 * 72 * 2];
    const int LOFS = 128 * 72;

    f32x4 accP[4][4], accQ[4][4];
#pragma unroll
    for (int i = 0; i < 4; i++)
#pragma unroll
        for (int j = 0; j < 4; j++) {
            accP[i][j] = (f32x4){0.f, 0.f, 0.f, 0.f};
            accQ[i][j] = (f32x4){0.f, 0.f, 0.f, 0.f};
        }

    const int srow = tid >> 1, shalf = tid & 1;
    const float* Asrc  = v   + (size_t)(bm * 128 + srow) * 512 + shalf * 32;
    const float* W1src = Wp  + (size_t)(bn * 128 + srow) * 512 + shalf * 32;
    const float* W2src = Wp_ + (size_t)(bn * 128 + srow) * 512 + shalf * 32;
    unsigned short* Adst = Al + srow * 72 + shalf * 32;
    unsigned short* Wdst = Wl + srow * 72 + shalf * 32;

    for (int k0 = 0; k0 < 512; k0 += 64) {
        __syncthreads();
#pragma unroll
        for (int j = 0; j < 4; j++) {
            f32x4 x = *(const f32x4*)(Asrc + k0 + j * 8);
            f32x4 y = *(const f32x4*)(Asrc + k0 + j * 8 + 4);
            s16x8 hi, lo; split8(x, y, &hi, &lo);
            *(s16x8*)(Adst + j * 8) = hi;
            *(s16x8*)(Adst + LOFS + j * 8) = lo;
        }
#pragma unroll
        for (int j = 0; j < 4; j++) {
            f32x4 x = *(const f32x4*)(W1src + k0 + j * 8);
            f32x4 y = *(const f32x4*)(W1src + k0 + j * 8 + 4);
            s16x8 hi, lo; split8(x, y, &hi, &lo);
            *(s16x8*)(Wdst + j * 8) = hi;
            *(s16x8*)(Wdst + LOFS + j * 8) = lo;
        }
        __syncthreads();

#pragma unroll
        for (int kt = 0; kt < 2; kt++) {
            s16x8 afh[4], afl[4], bfh[4], bfl[4];
#pragma unroll
            for (int mb = 0; mb < 4; mb++) {
                afh[mb] = *(const s16x8*)(Al + ((w & 1) * 64 + mb * 16 + l15) * 72 + kt * 32 + l4 * 8);
                afl[mb] = *(const s16x8*)(Al + LOFS + ((w & 1) * 64 + mb * 16 + l15) * 72 + kt * 32 + l4 * 8);
            }
#pragma unroll
            for (int nb = 0; nb < 4; nb++) {
                bfh[nb] = *(const s16x8*)(Wl + ((w >> 1) * 64 + nb * 16 + l15) * 72 + kt * 32 + l4 * 8);
                bfl[nb] = *(const s16x8*)(Wl + LOFS + ((w >> 1) * 64 + nb * 16 + l15) * 72 + kt * 32 + l4 * 8);
            }
#pragma unroll
            for (int mb = 0; mb < 4; mb++)
#pragma unroll
                for (int nb = 0; nb < 4; nb++) {
                    accP[mb][nb] = mfma16(afh[mb], bfh[nb], accP[mb][nb]);
                    accP[mb][nb] = mfma16(afh[mb], bfl[nb], accP[mb][nb]);
                    accP[mb][nb] = mfma16(afl[mb], bfh[nb], accP[mb][nb]);
                }
        }

        __syncthreads();
#pragma unroll
        for (int j = 0; j < 4; j++) {
            f32x4 x = *(const f32x4*)(W2src + k0 + j * 8);
            f32x4 y = *(const f32x4*)(W2src + k0 + j * 8 + 4);
            s16x8 hi, lo; split8(x, y, &hi, &lo);
            *(s16x8*)(Wdst + j * 8) = hi;
            *(s16x8*)(Wdst + LOFS + j * 8) = lo;
        }
        __syncthreads();

#pragma unroll
        for (int kt = 0; kt < 2; kt++) {
            s16x8 afh[4], afl[4], bfh[4], bfl[4];
#pragma unroll
            for (int mb = 0; mb < 4; mb++) {
                afh[mb] = *(const s16x8*)(Al + ((w & 1) * 64 + mb * 16 + l15) * 72 + kt * 32 + l4 * 8);
                afl[mb] = *(const s16x8*)(Al + LOFS + ((w & 1) * 64 + mb * 16 + l15) * 72 + kt * 32 + l4 * 8);
            }
#pragma unroll
            for (int nb = 0; nb < 4; nb++) {
                bfh[nb] = *(const s16x8*)(Wl + ((w >> 1) * 64 + nb * 16 + l15) * 72 + kt * 32 + l4 * 8);
                bfl[nb] = *(const s16x8*)(Wl + LOFS + ((w >> 1) * 64 + nb * 16 + l15) * 72 + kt * 32 + l4 * 8);
            }
#pragma unroll
            for (int mb = 0; mb < 4; mb++)
#pragma unroll
                for (int nb = 0; nb < 4; nb++) {
                    accQ[mb][nb] = mfma16(afh[mb], bfh[nb], accQ[mb][nb]);
                    accQ[mb][nb] = mfma16(afh[mb], bfl[nb], accQ[mb][nb]);
                    accQ[mb][nb] = mfma16(afl[mb], bfh[nb], accQ[mb][nb]);
                }
        }
    }

    const int m0 = bm * 128 + (w & 1) * 64;
    const int n0 = bn * 128 + (w >> 1) * 64;
#pragma unroll
    for (int nb = 0; nb < 4; nb++) {
        const int n = n0 + nb * 16 + l15;
#pragma unroll
        for (int mb = 0; mb < 4; mb++) {
#pragma unroll
            for (int i = 0; i < 4; i++) {
                const int m = m0 + mb * 16 + l4 * 4 + i;
                Ep[(size_t)m * 512 + n] = __expf(2.0f * accP[mb][nb][i]);
                Eq[(size_t)m * 512 + n] = __expf(2.0f * accQ[mb][nb][i]);
            }
        }
    }
}

// ---------------------------------------------------------------------------
// Gi GEMM (r8-proven, AIN bf16 path only)
// ---------------------------------------------------------------------------
__global__ __launch_bounds__(256, 2)
void gi_k(const unsigned short* __restrict__ Ap, const float* __restrict__ Wp,
          const float* __restrict__ bias, unsigned short* __restrict__ outp, int N)
{
    const int bm = blockIdx.x, bn = blockIdx.y;
    const int tid = threadIdx.x;
    const int w = tid >> 6, lane = tid & 63;
    const int l15 = lane & 15, l4 = lane >> 4;

    __shared__ unsigned short Al[128 * 72];
    __shared__ unsigned short Wl[128 * 72];

    f32x4 acc[4][4];
#pragma unroll
    for (int i = 0; i < 4; i++)
#pragma unroll
        for (int j = 0; j < 4; j++) acc[i][j] = (f32x4){0.f, 0.f, 0.f, 0.f};

    const int srow = tid >> 1, shalf = tid & 1;
    const unsigned short* Asrcb = Ap + (size_t)(bm * 128 + srow) * 512 + shalf * 32;
    const float* Wsrc = Wp + (size_t)(bn * 128 + srow) * 512 + shalf * 32;
    unsigned short* Adst = Al + srow * 72 + shalf * 32;
    unsigned short* Wdst = Wl + srow * 72 + shalf * 32;

    for (int k0 = 0; k0 < 512; k0 += 64) {
        __syncthreads();
#pragma unroll
        for (int j = 0; j < 4; j++)
            *(s16x8*)(Adst + j * 8) = *(const s16x8*)(Asrcb + k0 + j * 8);
#pragma unroll
        for (int j = 0; j < 4; j++) {
            f32x4 x = *(const f32x4*)(Wsrc + k0 + j * 8);
            f32x4 y = *(const f32x4*)(Wsrc + k0 + j * 8 + 4);
            *(s16x8*)(Wdst + j * 8) = pack8(x, y);
        }
        __syncthreads();

#pragma unroll
        for (int kt = 0; kt < 2; kt++) {
            s16x8 afh[4], bfh[4];
#pragma unroll
            for (int mb = 0; mb < 4; mb++)
                afh[mb] = *(const s16x8*)(Al + ((w & 1) * 64 + mb * 16 + l15) * 72 + kt * 32 + l4 * 8);
#pragma unroll
            for (int nb = 0; nb < 4; nb++)
                bfh[nb] = *(const s16x8*)(Wl + ((w >> 1) * 64 + nb * 16 + l15) * 72 + kt * 32 + l4 * 8);
#pragma unroll
            for (int mb = 0; mb < 4; mb++)
#pragma unroll
                for (int nb = 0; nb < 4; nb++)
                    acc[mb][nb] = mfma16(afh[mb], bfh[nb], acc[mb][nb]);
        }
    }

    const int m0 = bm * 128 + (w & 1) * 64;
    const int n0 = bn * 128 + (w >> 1) * 64;
#pragma unroll
    for (int nb = 0; nb < 4; nb++) {
        const int n = n0 + nb * 16 + l15;
        const float bv = bias[n];
#pragma unroll
        for (int mb = 0; mb < 4; mb++) {
#pragma unroll
            for (int i = 0; i < 4; i++) {
                const int m = m0 + mb * 16 + l4 * 4 + i;
                outp[(size_t)m * N + n] = f2bf(acc[mb][nb][i] + bv);
            }
        }
    }
}

// ---------------------------------------------------------------------------
// Fused attention, exp-form logits. block = (t-tile of 16, b). 512 threads.
// ---------------------------------------------------------------------------
__global__ __launch_bounds__(512, 4)
void att_k(const float* __restrict__ Ept, const float* __restrict__ Eqt,
           const float* __restrict__ Vv, const float* __restrict__ vin,
           unsigned short* __restrict__ cbuf)
{
    const int tblk = blockIdx.x, b = blockIdx.y;
    const int tid = threadIdx.x;
    const int w = tid >> 6, lane = tid & 63;
    const int t_in = lane >> 5, sl = lane & 31;
    const int t_loc = w * 2 + t_in;          // 0..15
    const int tg = tblk * 16 + t_loc;        // global t

    __shared__ float sbuf[16][513];
    __shared__ float qst[8][640];
    __shared__ float zinv[16];

    float Ep[16], Vb2[16];
    float VbS = 0.0f;
    {
        const float* pp = Ept + ((size_t)tg * 64 + b) * 512 + sl * 16;
        const float* vb = Vv + (size_t)b * 512 + sl * 16;
#pragma unroll
        for (int j = 0; j < 4; j++) {
            f32x4 x = *(const f32x4*)(pp + j * 4);
            f32x4 y = *(const f32x4*)(vb + j * 4);
#pragma unroll
            for (int e = 0; e < 4; e++) {
                Ep[j * 4 + e] = x[e];
                Vb2[j * 4 + e] = 2.0f * y[e];
                VbS += y[e];
            }
        }
    }

    // ---- Phase A: logits.  term = Vb - 2*Vb*rcp(1 + Ep*Eq) ----
    for (int l0 = 0; l0 < 512; l0 += 8) {
        __syncthreads();
        {
            const int row = tid >> 6;
            const int cb = (tid & 63) * 8;
            const float* src = Eqt + ((size_t)(l0 + row) * 64 + b) * 512 + cb;
            const int f0 = cb + 4 * (cb >> 4);
            *(f32x4*)(&qst[row][f0])     = *(const f32x4*)(src);
            *(f32x4*)(&qst[row][f0 + 4]) = *(const f32x4*)(src + 4);
        }
        __syncthreads();
        for (int l = 0; l < 8; l++) {
            const float* qrow = &qst[l][sl * 20];
            float a0 = VbS, a1 = 0.f, a2 = 0.f, a3 = 0.f;
#pragma unroll
            for (int j = 0; j < 4; j++) {
                f32x4 q = *(const f32x4*)(qrow + j * 4);
                {
                    float d = fmaf(Ep[4 * j + 0], q[0], 1.0f);
                    a0 = fmaf(-Vb2[4 * j + 0], rcp_fast(d), a0);
                }
                {
                    float d = fmaf(Ep[4 * j + 1], q[1], 1.0f);
                    a1 = fmaf(-Vb2[4 * j + 1], rcp_fast(d), a1);
                }
                {
                    float d = fmaf(Ep[4 * j + 2], q[2], 1.0f);
                    a2 = fmaf(-Vb2[4 * j + 2], rcp_fast(d), a2);
                }
                {
                    float d = fmaf(Ep[4 * j + 3], q[3], 1.0f);
                    a3 = fmaf(-Vb2[4 * j + 3], rcp_fast(d), a3);
                }
            }
            float accp = (a0 + a1) + (a2 + a3);
#pragma unroll
            for (int m = 1; m < 32; m <<= 1) accp += __shfl_xor(accp, m, 64);
            if (sl == 0) sbuf[t_loc][l0 + l] = accp;
        }
    }
    __syncthreads();

    // ---- Phase B: softmax over l ----
    {
        const int tr = tid >> 5;
        const int i = tid & 31;
        float m = -1e30f;
        for (int l = i; l < 512; l += 32) m = fmaxf(m, sbuf[tr][l]);
#pragma unroll
        for (int mm = 1; mm < 32; mm <<= 1) m = fmaxf(m, __shfl_xor(m, mm, 64));
        float z = 0.0f;
        for (int l = i; l < 512; l += 32) {
            float e = __expf(sbuf[tr][l] - m);
            sbuf[tr][l] = e;
            z += e;
        }
#pragma unroll
        for (int mm = 1; mm < 32; mm <<= 1) z += __shfl_xor(z, mm, 64);
        if (i == 0) zinv[tr] = rcp_fast(z);
    }
    __syncthreads();

    // ---- Phase C: c[t][b][:] ----
    float ca[16];
#pragma unroll
    for (int j = 0; j < 16; j++) ca[j] = 0.0f;

    for (int l0 = 0; l0 < 512; l0 += 8) {
        __syncthreads();
        {
            const int row = tid >> 6;
            const int cb = (tid & 63) * 8;
            const float* src = vin + ((size_t)(l0 + row) * 64 + b) * 512 + cb;
            const int f0 = cb + 4 * (cb >> 4);
            *(f32x4*)(&qst[row][f0])     = *(const f32x4*)(src);
            *(f32x4*)(&qst[row][f0 + 4]) = *(const f32x4*)(src + 4);
        }
        __syncthreads();
        for (int l = 0; l < 8; l++) {
            const float a = sbuf[t_loc][l0 + l];
            const float* vrow = &qst[l][sl * 20];
#pragma unroll
            for (int j = 0; j < 4; j++) {
                f32x4 x = *(const f32x4*)(vrow + j * 4);
                ca[4 * j + 0] = fmaf(a, x[0], ca[4 * j + 0]);
                ca[4 * j + 1] = fmaf(a, x[1], ca[4 * j + 1]);
                ca[4 * j + 2] = fmaf(a, x[2], ca[4 * j + 2]);
                ca[4 * j + 3] = fmaf(a, x[3], ca[4 * j + 3]);
            }
        }
    }
    const float zi = zinv[t_loc];
    unsigned short* co = cbuf + ((size_t)tg * 64 + b) * 512 + sl * 16;
#pragma unroll
    for (int j = 0; j < 4; j++) {
        s16x4 o;
        o[0] = (short)f2bf(ca[4 * j + 0] * zi);
        o[1] = (short)f2bf(ca[4 * j + 1] * zi);
        o[2] = (short)f2bf(ca[4 * j + 2] * zi);
        o[3] = (short)f2bf(ca[4 * j + 3] * zi);
        *(s16x4*)(co + j * 4) = o;
    }
}

// ---------------------------------------------------------------------------
// rec_k v11 — r8's measured path only. 64 blocks x 256 threads:
//   g = bid>>3 owns b in [g*8, +8); sub = bid&7 owns j in [sub*64, +64);
//   wave w owns 16 j's. W_hh register-resident.
// Per step: dwordx4 sc1 h loads -> 48 MFMA -> gates -> sc1 h publish ->
//   vm_drain + __syncthreads -> tid0 agent flag add -> hs store + Gi prefetch
//   (drain during poll) -> poll flag >= 8.
// ---------------------------------------------------------------------------
__global__ __launch_bounds__(256, 1)
void rec_k(const unsigned short* __restrict__ Gi,
           const float* __restrict__ Whh, const float* __restrict__ bhh,
           const float* __restrict__ h0,
           unsigned int* __restrict__ hb32,
           unsigned int* __restrict__ bar,
           float* __restrict__ hs)
{
    const int tid = threadIdx.x;
    const int g = blockIdx.x >> 3;
    const int sub = blockIdx.x & 7;
    const int w = tid >> 6;
    const int lane = tid & 63;
    const int l15 = lane & 15, l4 = lane >> 4;
    const int b  = g * 8 + (l15 & 7);
    const int jb = sub * 64 + w * 16;
    const int jrow = l4 * 4;
    const bool writer = (l15 < 8);

    s16x8 wf[3][16];
#pragma unroll
    for (int gg = 0; gg < 3; gg++) {
        const float* wr = Whh + (size_t)(gg * 512 + jb + l15) * 512 + l4 * 8;
#pragma unroll
        for (int c = 0; c < 16; c++) {
            f32x4 x = *(const f32x4*)(wr + c * 32);
            f32x4 y = *(const f32x4*)(wr + c * 32 + 4);
            wf[gg][c] = pack8(x, y);
        }
    }

    float bh_r[4], bh_z[4], bh_n[4];
#pragma unroll
    for (int i = 0; i < 4; i++) {
        bh_r[i] = bhh[jb + jrow + i];
        bh_z[i] = bhh[512 + jb + jrow + i];
        bh_n[i] = bhh[1024 + jb + jrow + i];
    }
    float hp[4];
#pragma unroll
    for (int i = 0; i < 4; i++) hp[i] = h0[(size_t)b * 512 + jb + jrow + i];

    unsigned* barA = bar + g * 512;

    s16x4 g0, g1, g2;
    {
        const unsigned short* gp = Gi + (size_t)b * 1536 + jb + jrow;
        g0 = *(const s16x4*)(gp);
        g1 = *(const s16x4*)(gp + 512);
        g2 = *(const s16x4*)(gp + 1024);
    }

#define LDH(i, lit) asm volatile("global_load_dwordx4 %0, %1, off offset:" lit " sc1" \
                                 : "=v"(hfrag2[i]) : "v"(src) : "memory");

    for (int t = 0; t < 512; t++) {
        s16x8 hfrag[16];
        if (t == 0) {
            const float* hr = h0 + (size_t)b * 512 + l4 * 8;
#pragma unroll
            for (int c = 0; c < 16; c++) {
                f32x4 x = *(const f32x4*)(hr + c * 32);
                f32x4 y = *(const f32x4*)(hr + c * 32 + 4);
                hfrag[c] = pack8(x, y);
            }
        } else {
            const unsigned int* src = hb32 + (t & 1) * 16384 + b * 256 + l4 * 4;
            s16x8 hfrag2[16];
            LDH(0, "0")   LDH(1, "64")  LDH(2, "128")  LDH(3, "192")
            LDH(4, "256") LDH(5, "320") LDH(6, "384")  LDH(7, "448")
            LDH(8, "512") LDH(9, "576") LDH(10, "640") LDH(11, "704")
            LDH(12, "768") LDH(13, "832") LDH(14, "896") LDH(15, "960")
            vm_drain();
            __builtin_amdgcn_sched_barrier(0);
#pragma unroll
            for (int c = 0; c < 16; c++) hfrag[c] = hfrag2[c];
        }

        f32x4 acc0 = {0.f, 0.f, 0.f, 0.f};
        f32x4 acc1 = {0.f, 0.f, 0.f, 0.f};
        f32x4 acc2 = {0.f, 0.f, 0.f, 0.f};
#pragma unroll
        for (int c = 0; c < 16; c++) {
            acc0 = mfma16(wf[0][c], hfrag[c], acc0);
            acc1 = mfma16(wf[1][c], hfrag[c], acc1);
            acc2 = mfma16(wf[2][c], hfrag[c], acc2);
        }

#pragma unroll
        for (int i = 0; i < 4; i++) {
            float rr = sigmoid_fast(bf2f((unsigned short)g0[i]) + acc0[i] + bh_r[i]);
            float zz = sigmoid_fast(bf2f((unsigned short)g1[i]) + acc1[i] + bh_z[i]);
            float nn = tanh_fast(bf2f((unsigned short)g2[i]) + rr * (acc2[i] + bh_n[i]));
            hp[i] = fmaf(zz, hp[i] - nn, nn);
        }

        float* hso = hs + ((size_t)t * 64 + b) * 512 + jb + jrow;
        f32x4 hv = {hp[0], hp[1], hp[2], hp[3]};

        if (t < 511) {
            // publish h_{t+1}: sc1 write-through (MALL-visible on any placement)
            if (writer) {
                u32x2 pp;
                pp[0] = (unsigned)f2bf(hp[0]) | ((unsigned)f2bf(hp[1]) << 16);
                pp[1] = (unsigned)f2bf(hp[2]) | ((unsigned)f2bf(hp[3]) << 16);
                unsigned int* dst = hb32 + ((t + 1) & 1) * 16384 + b * 256 + ((jb + jrow) >> 1);
                asm volatile("global_store_dwordx2 %0, %1, off sc1"
                             :: "v"(dst), "v"(pp) : "memory");
            }
            vm_drain();
            __syncthreads();                       // all waves' stores at MALL
            if (tid == 0) add_agent(barA + t, 1u);

            // hidden under the wait: hs store + Gi[t+1] prefetch (plain, L2-ok:
            // Gi comes from the prior dispatch -> kernel-boundary coherence)
            if (writer) *(f32x4*)hso = hv;
            s16x4 n0, n1, n2;
            {
                const unsigned short* gp = Gi + ((size_t)(t + 1) * 64 + b) * 1536 + jb + jrow;
                n0 = *(const s16x4*)(gp);
                n1 = *(const s16x4*)(gp + 512);
                n2 = *(const s16x4*)(gp + 1024);
            }

            for (;;) {
                unsigned vb = ld_agent(barA + t);
                if (vb >= 8u) break;
                __builtin_amdgcn_s_sleep(1);
            }
            g0 = n0; g1 = n1; g2 = n2;
        } else {
            if (writer) *(f32x4*)hso = hv;
        }
    }
#undef LDH
}

// ---------------------------------------------------------------------------
// ws layout (bytes):
//   Ep (Pt) : [0, 64Mi)        f32
//   Eq (Qt) : [64Mi, 128Mi)    f32
//   c       : [128Mi, 160Mi)   bf16
//   Gi      : [0, 96Mi)        bf16 (overlays Ep/Eq, dead by then)
//   hb32    : [160Mi, +128Ki)  u32 bf16-pairs (agent/sc1 ops)
//   bar     : [160Mi+128Ki, +16Ki) u32 8 x 512 (memset per launch)
// ---------------------------------------------------------------------------
extern "C" void kernel_launch(void* const* d_in, const int* in_sizes, int n_in,
                              void* d_out, int out_size, void* d_ws, size_t ws_size,
                              hipStream_t stream)
{
    (void)in_sizes; (void)n_in; (void)out_size; (void)ws_size;
    const float* v   = (const float*)d_in[0];
    const float* h0  = (const float*)d_in[1];
    const float* Vv  = (const float*)d_in[2];
    const float* Wp  = (const float*)d_in[3];
    const float* Wp_ = (const float*)d_in[4];
    const float* Wih = (const float*)d_in[5];
    const float* Whh = (const float*)d_in[6];
    const float* bih = (const float*)d_in[7];
    const float* bhh = (const float*)d_in[8];
    float* hs = (float*)d_out;

    char* ws = (char*)d_ws;
    float* Ep = (float*)(ws);
    float* Eq = (float*)(ws + 67108864ULL);
    unsigned short* cb  = (unsigned short*)(ws + 134217728ULL);
    unsigned short* Gi  = (unsigned short*)(ws);
    unsigned int*   hb32 = (unsigned int*)(ws + 167772160ULL);
    unsigned int*   bar  = (unsigned int*)(ws + 167772160ULL + 131072ULL);

    hipMemsetAsync(bar, 0, 4096 * sizeof(unsigned int), stream);

    pq_k<<<dim3(256, 4), 256, 0, stream>>>(v, Wp, Wp_, Ep, Eq);

    att_k<<<dim3(32, 64), 512, 0, stream>>>(Ep, Eq, Vv, v, cb);

    gi_k<<<dim3(256, 12), 256, 0, stream>>>(cb, Wih, bih, Gi, 1536);

    rec_k<<<dim3(64), 256, 0, stream>>>(Gi, Whh, bhh, h0, hb32, bar, hs);
}

// Round 15
// 3847.812 us; speedup vs baseline: 1.8892x; 1.0244x over previous
//
#include <hip/hip_runtime.h>
#include <hip/hip_bf16.h>

// L=512, B=64, D=H=512, 3H=1536.
//  pq_k: fused Ep = exp(2·v@Wp^T), Eq = exp(2·v@Wp_^T)  (split-bf16 3-pass MFMA,
//        A-tile staged once, W tiles sequential in same LDS)
//  att_k: logits via exp form Vb·tanh(p+q) = Vb − 2Vb·rcp(1+Ep·Eq), with
//        PAIRED reciprocals (a/d0 + a'/d1 = (a·d1+a'·d0)·rcp(d0·d1)):
//        trans-pipe work halves (rcp was the binding pipe at quarter rate).
//  gi_k: Gi = c@W_ih^T + b_ih  (bf16)
//  rec_k v11 (r14-proven): 64 blocks, 8 groups x 8 blocks x 4 waves, W_hh
//        register-resident, sc1 h exchange (dwordx4 loads), per-block agent
//        flag + poll.

typedef float f32x4 __attribute__((ext_vector_type(4)));
typedef short s16x8 __attribute__((ext_vector_type(8)));
typedef short s16x4 __attribute__((ext_vector_type(4)));
typedef unsigned int u32x2 __attribute__((ext_vector_type(2)));

static __device__ __forceinline__ float rcp_fast(float x) { return __builtin_amdgcn_rcpf(x); }
static __device__ __forceinline__ float tanh_fast(float x) {
    float e = __expf(2.0f * x);
    return 1.0f - 2.0f * rcp_fast(e + 1.0f);
}
static __device__ __forceinline__ float sigmoid_fast(float x) {
    return rcp_fast(1.0f + __expf(-x));
}
static __device__ __forceinline__ unsigned short f2bf(float x) {
    union { float f; unsigned u; } v; v.f = x;
    unsigned r = v.u + 0x7FFFu + ((v.u >> 16) & 1u);
    return (unsigned short)(r >> 16);
}
static __device__ __forceinline__ float bf2f(unsigned short b) {
    union { unsigned u; float f; } v; v.u = ((unsigned)b) << 16;
    return v.f;
}
static __device__ __forceinline__ s16x8 pack8(f32x4 a, f32x4 b) {
    s16x8 r;
    r[0] = (short)f2bf(a[0]); r[1] = (short)f2bf(a[1]);
    r[2] = (short)f2bf(a[2]); r[3] = (short)f2bf(a[3]);
    r[4] = (short)f2bf(b[0]); r[5] = (short)f2bf(b[1]);
    r[6] = (short)f2bf(b[2]); r[7] = (short)f2bf(b[3]);
    return r;
}
static __device__ __forceinline__ void split8(f32x4 a, f32x4 b, s16x8* hi, s16x8* lo) {
    s16x8 h, l;
#pragma unroll
    for (int e = 0; e < 4; e++) {
        unsigned short hh = f2bf(a[e]); h[e] = (short)hh;
        l[e] = (short)f2bf(a[e] - bf2f(hh));
    }
#pragma unroll
    for (int e = 0; e < 4; e++) {
        unsigned short hh = f2bf(b[e]); h[4 + e] = (short)hh;
        l[4 + e] = (short)f2bf(b[e] - bf2f(hh));
    }
    *hi = h; *lo = l;
}
static __device__ __forceinline__ f32x4 mfma16(s16x8 a, s16x8 b, f32x4 c) {
    return __builtin_amdgcn_mfma_f32_16x16x32_bf16(a, b, c, 0, 0, 0);
}
static __device__ __forceinline__ unsigned ld_agent(const unsigned* p) {
    return __hip_atomic_load(p, __ATOMIC_RELAXED, __HIP_MEMORY_SCOPE_AGENT);
}
static __device__ __forceinline__ void add_agent(unsigned* p, unsigned v) {
    __hip_atomic_fetch_add(p, v, __ATOMIC_RELAXED, __HIP_MEMORY_SCOPE_AGENT);
}
static __device__ __forceinline__ void vm_drain() {
    asm volatile("s_waitcnt vmcnt(0)" ::: "memory");
}

// ---------------------------------------------------------------------------
// Fused P/Q GEMM (r14-proven)
// ---------------------------------------------------------------------------
__global__ __launch_bounds__(256, 2)
void pq_k(const float* __restrict__ v, const float* __restrict__ Wp,
          const float* __restrict__ Wp_, float* __restrict__ Ep,
          float* __restrict__ Eq)
{
    const int bm = blockIdx.x, bn = blockIdx.y;
    const int tid = threadIdx.x;
    const int w = tid >> 6, lane = tid & 63;
    const int l15 = lane & 15, l4 = lane >> 4;

    __shared__ unsigned short Al[128 * 72 * 2];
    __shared__ unsigned short Wl[128 * 72 * 2];
    const int LOFS = 128 * 72;

    f32x4 accP[4][4], accQ[4][4];
#pragma unroll
    for (int i = 0; i < 4; i++)
#pragma unroll
        for (int j = 0; j < 4; j++) {
            accP[i][j] = (f32x4){0.f, 0.f, 0.f, 0.f};
            accQ[i][j] = (f32x4){0.f, 0.f, 0.f, 0.f};
        }

    const int srow = tid >> 1, shalf = tid & 1;
    const float* Asrc  = v   + (size_t)(bm * 128 + srow) * 512 + shalf * 32;
    const float* W1src = Wp  + (size_t)(bn * 128 + srow) * 512 + shalf * 32;
    const float* W2src = Wp_ + (size_t)(bn * 128 + srow) * 512 + shalf * 32;
    unsigned short* Adst = Al + srow * 72 + shalf * 32;
    unsigned short* Wdst = Wl + srow * 72 + shalf * 32;

    for (int k0 = 0; k0 < 512; k0 += 64) {
        __syncthreads();
#pragma unroll
        for (int j = 0; j < 4; j++) {
            f32x4 x = *(const f32x4*)(Asrc + k0 + j * 8);
            f32x4 y = *(const f32x4*)(Asrc + k0 + j * 8 + 4);
            s16x8 hi, lo; split8(x, y, &hi, &lo);
            *(s16x8*)(Adst + j * 8) = hi;
            *(s16x8*)(Adst + LOFS + j * 8) = lo;
        }
#pragma unroll
        for (int j = 0; j < 4; j++) {
            f32x4 x = *(const f32x4*)(W1src + k0 + j * 8);
            f32x4 y = *(const f32x4*)(W1src + k0 + j * 8 + 4);
            s16x8 hi, lo; split8(x, y, &hi, &lo);
            *(s16x8*)(Wdst + j * 8) = hi;
            *(s16x8*)(Wdst + LOFS + j * 8) = lo;
        }
        __syncthreads();

#pragma unroll
        for (int kt = 0; kt < 2; kt++) {
            s16x8 afh[4], afl[4], bfh[4], bfl[4];
#pragma unroll
            for (int mb = 0; mb < 4; mb++) {
                afh[mb] = *(const s16x8*)(Al + ((w & 1) * 64 + mb * 16 + l15) * 72 + kt * 32 + l4 * 8);
                afl[mb] = *(const s16x8*)(Al + LOFS + ((w & 1) * 64 + mb * 16 + l15) * 72 + kt * 32 + l4 * 8);
            }
#pragma unroll
            for (int nb = 0; nb < 4; nb++) {
                bfh[nb] = *(const s16x8*)(Wl + ((w >> 1) * 64 + nb * 16 + l15) * 72 + kt * 32 + l4 * 8);
                bfl[nb] = *(const s16x8*)(Wl + LOFS + ((w >> 1) * 64 + nb * 16 + l15) * 72 + kt * 32 + l4 * 8);
            }
#pragma unroll
            for (int mb = 0; mb < 4; mb++)
#pragma unroll
                for (int nb = 0; nb < 4; nb++) {
                    accP[mb][nb] = mfma16(afh[mb], bfh[nb], accP[mb][nb]);
                    accP[mb][nb] = mfma16(afh[mb], bfl[nb], accP[mb][nb]);
                    accP[mb][nb] = mfma16(afl[mb], bfh[nb], accP[mb][nb]);
                }
        }

        __syncthreads();
#pragma unroll
        for (int j = 0; j < 4; j++) {
            f32x4 x = *(const f32x4*)(W2src + k0 + j * 8);
            f32x4 y = *(const f32x4*)(W2src + k0 + j * 8 + 4);
            s16x8 hi, lo; split8(x, y, &hi, &lo);
            *(s16x8*)(Wdst + j * 8) = hi;
            *(s16x8*)(Wdst + LOFS + j * 8) = lo;
        }
        __syncthreads();

#pragma unroll
        for (int kt = 0; kt < 2; kt++) {
            s16x8 afh[4], afl[4], bfh[4], bfl[4];
#pragma unroll
            for (int mb = 0; mb < 4; mb++) {
                afh[mb] = *(const s16x8*)(Al + ((w & 1) * 64 + mb * 16 + l15) * 72 + kt * 32 + l4 * 8);
                afl[mb] = *(const s16x8*)(Al + LOFS + ((w & 1) * 64 + mb * 16 + l15) * 72 + kt * 32 + l4 * 8);
            }
#pragma unroll
            for (int nb = 0; nb < 4; nb++) {
                bfh[nb] = *(const s16x8*)(Wl + ((w >> 1) * 64 + nb * 16 + l15) * 72 + kt * 32 + l4 * 8);
                bfl[nb] = *(const s16x8*)(Wl + LOFS + ((w >> 1) * 64 + nb * 16 + l15) * 72 + kt * 32 + l4 * 8);
            }
#pragma unroll
            for (int mb = 0; mb < 4; mb++)
#pragma unroll
                for (int nb = 0; nb < 4; nb++) {
                    accQ[mb][nb] = mfma16(afh[mb], bfh[nb], accQ[mb][nb]);
                    accQ[mb][nb] = mfma16(afh[mb], bfl[nb], accQ[mb][nb]);
                    accQ[mb][nb] = mfma16(afl[mb], bfh[nb], accQ[mb][nb]);
                }
        }
    }

    const int m0 = bm * 128 + (w & 1) * 64;
    const int n0 = bn * 128 + (w >> 1) * 64;
#pragma unroll
    for (int nb = 0; nb < 4; nb++) {
        const int n = n0 + nb * 16 + l15;
#pragma unroll
        for (int mb = 0; mb < 4; mb++) {
#pragma unroll
            for (int i = 0; i < 4; i++) {
                const int m = m0 + mb * 16 + l4 * 4 + i;
                Ep[(size_t)m * 512 + n] = __expf(2.0f * accP[mb][nb][i]);
                Eq[(size_t)m * 512 + n] = __expf(2.0f * accQ[mb][nb][i]);
            }
        }
    }
}

// ---------------------------------------------------------------------------
// Gi GEMM (r14-proven)
// ---------------------------------------------------------------------------
__global__ __launch_bounds__(256, 2)
void gi_k(const unsigned short* __restrict__ Ap, const float* __restrict__ Wp,
          const float* __restrict__ bias, unsigned short* __restrict__ outp, int N)
{
    const int bm = blockIdx.x, bn = blockIdx.y;
    const int tid = threadIdx.x;
    const int w = tid >> 6, lane = tid & 63;
    const int l15 = lane & 15, l4 = lane >> 4;

    __shared__ unsigned short Al[128 * 72];
    __shared__ unsigned short Wl[128 * 72];

    f32x4 acc[4][4];
#pragma unroll
    for (int i = 0; i < 4; i++)
#pragma unroll
        for (int j = 0; j < 4; j++) acc[i][j] = (f32x4){0.f, 0.f, 0.f, 0.f};

    const int srow = tid >> 1, shalf = tid & 1;
    const unsigned short* Asrcb = Ap + (size_t)(bm * 128 + srow) * 512 + shalf * 32;
    const float* Wsrc = Wp + (size_t)(bn * 128 + srow) * 512 + shalf * 32;
    unsigned short* Adst = Al + srow * 72 + shalf * 32;
    unsigned short* Wdst = Wl + srow * 72 + shalf * 32;

    for (int k0 = 0; k0 < 512; k0 += 64) {
        __syncthreads();
#pragma unroll
        for (int j = 0; j < 4; j++)
            *(s16x8*)(Adst + j * 8) = *(const s16x8*)(Asrcb + k0 + j * 8);
#pragma unroll
        for (int j = 0; j < 4; j++) {
            f32x4 x = *(const f32x4*)(Wsrc + k0 + j * 8);
            f32x4 y = *(const f32x4*)(Wsrc + k0 + j * 8 + 4);
            *(s16x8*)(Wdst + j * 8) = pack8(x, y);
        }
        __syncthreads();

#pragma unroll
        for (int kt = 0; kt < 2; kt++) {
            s16x8 afh[4], bfh[4];
#pragma unroll
            for (int mb = 0; mb < 4; mb++)
                afh[mb] = *(const s16x8*)(Al + ((w & 1) * 64 + mb * 16 + l15) * 72 + kt * 32 + l4 * 8);
#pragma unroll
            for (int nb = 0; nb < 4; nb++)
                bfh[nb] = *(const s16x8*)(Wl + ((w >> 1) * 64 + nb * 16 + l15) * 72 + kt * 32 + l4 * 8);
#pragma unroll
            for (int mb = 0; mb < 4; mb++)
#pragma unroll
                for (int nb = 0; nb < 4; nb++)
                    acc[mb][nb] = mfma16(afh[mb], bfh[nb], acc[mb][nb]);
        }
    }

    const int m0 = bm * 128 + (w & 1) * 64;
    const int n0 = bn * 128 + (w >> 1) * 64;
#pragma unroll
    for (int nb = 0; nb < 4; nb++) {
        const int n = n0 + nb * 16 + l15;
        const float bv = bias[n];
#pragma unroll
        for (int mb = 0; mb < 4; mb++) {
#pragma unroll
            for (int i = 0; i < 4; i++) {
                const int m = m0 + mb * 16 + l4 * 4 + i;
                outp[(size_t)m * N + n] = f2bf(acc[mb][nb][i] + bv);
            }
        }
    }
}

// ---------------------------------------------------------------------------
// Fused attention, exp-form logits with PAIRED reciprocals.
// block = (t-tile of 16, b). 512 threads.
// ---------------------------------------------------------------------------
__global__ __launch_bounds__(512, 4)
void att_k(const float* __restrict__ Ept, const float* __restrict__ Eqt,
           const float* __restrict__ Vv, const float* __restrict__ vin,
           unsigned short* __restrict__ cbuf)
{
    const int tblk = blockIdx.x, b = blockIdx.y;
    const int tid = threadIdx.x;
    const int w = tid >> 6, lane = tid & 63;
    const int t_in = lane >> 5, sl = lane & 31;
    const int t_loc = w * 2 + t_in;          // 0..15
    const int tg = tblk * 16 + t_loc;        // global t

    __shared__ float sbuf[16][513];
    __shared__ float qst[8][640];
    __shared__ float zinv[16];

    float Ep[16], Vb2[16];
    float VbS = 0.0f;
    {
        const float* pp = Ept + ((size_t)tg * 64 + b) * 512 + sl * 16;
        const float* vb = Vv + (size_t)b * 512 + sl * 16;
#pragma unroll
        for (int j = 0; j < 4; j++) {
            f32x4 x = *(const f32x4*)(pp + j * 4);
            f32x4 y = *(const f32x4*)(vb + j * 4);
#pragma unroll
            for (int e = 0; e < 4; e++) {
                Ep[j * 4 + e] = x[e];
                Vb2[j * 4 + e] = 2.0f * y[e];
                VbS += y[e];
            }
        }
    }

    // ---- Phase A: logits, paired rcps:
    //   Σ Vb·tanh = ΣVb − Σ 2Vb·rcp(d);  d = 1+Ep·Eq
    //   pair: 2Vb0/d0 + 2Vb1/d1 = (2Vb0·d1 + 2Vb1·d0)·rcp(d0·d1)
    for (int l0 = 0; l0 < 512; l0 += 8) {
        __syncthreads();
        {
            const int row = tid >> 6;
            const int cb = (tid & 63) * 8;
            const float* src = Eqt + ((size_t)(l0 + row) * 64 + b) * 512 + cb;
            const int f0 = cb + 4 * (cb >> 4);
            *(f32x4*)(&qst[row][f0])     = *(const f32x4*)(src);
            *(f32x4*)(&qst[row][f0 + 4]) = *(const f32x4*)(src + 4);
        }
        __syncthreads();
        for (int l = 0; l < 8; l++) {
            const float* qrow = &qst[l][sl * 20];
            float a0 = VbS, a1 = 0.f;
#pragma unroll
            for (int j = 0; j < 4; j++) {
                f32x4 q = *(const f32x4*)(qrow + j * 4);
                float d0 = fmaf(Ep[4 * j + 0], q[0], 1.0f);
                float d1 = fmaf(Ep[4 * j + 1], q[1], 1.0f);
                float d2 = fmaf(Ep[4 * j + 2], q[2], 1.0f);
                float d3 = fmaf(Ep[4 * j + 3], q[3], 1.0f);
                float m01 = d0 * d1;
                float m23 = d2 * d3;
                float n01 = Vb2[4 * j + 0] * d1;
                n01 = fmaf(Vb2[4 * j + 1], d0, n01);
                float n23 = Vb2[4 * j + 2] * d3;
                n23 = fmaf(Vb2[4 * j + 3], d2, n23);
                a0 = fmaf(-n01, rcp_fast(m01), a0);
                a1 = fmaf(-n23, rcp_fast(m23), a1);
            }
            float accp = a0 + a1;
#pragma unroll
            for (int m = 1; m < 32; m <<= 1) accp += __shfl_xor(accp, m, 64);
            if (sl == 0) sbuf[t_loc][l0 + l] = accp;
        }
    }
    __syncthreads();

    // ---- Phase B: softmax over l ----
    {
        const int tr = tid >> 5;
        const int i = tid & 31;
        float m = -1e30f;
        for (int l = i; l < 512; l += 32) m = fmaxf(m, sbuf[tr][l]);
#pragma unroll
        for (int mm = 1; mm < 32; mm <<= 1) m = fmaxf(m, __shfl_xor(m, mm, 64));
        float z = 0.0f;
        for (int l = i; l < 512; l += 32) {
            float e = __expf(sbuf[tr][l] - m);
            sbuf[tr][l] = e;
            z += e;
        }
#pragma unroll
        for (int mm = 1; mm < 32; mm <<= 1) z += __shfl_xor(z, mm, 64);
        if (i == 0) zinv[tr] = rcp_fast(z);
    }
    __syncthreads();

    // ---- Phase C: c[t][b][:] ----
    float ca[16];
#pragma unroll
    for (int j = 0; j < 16; j++) ca[j] = 0.0f;

    for (int l0 = 0; l0 < 512; l0 += 8) {
        __syncthreads();
        {
            const int row = tid >> 6;
            const int cb = (tid & 63) * 8;
            const float* src = vin + ((size_t)(l0 + row) * 64 + b) * 512 + cb;
            const int f0 = cb + 4 * (cb >> 4);
            *(f32x4*)(&qst[row][f0])     = *(const f32x4*)(src);
            *(f32x4*)(&qst[row][f0 + 4]) = *(const f32x4*)(src + 4);
        }
        __syncthreads();
        for (int l = 0; l < 8; l++) {
            const float a = sbuf[t_loc][l0 + l];
            const float* vrow = &qst[l][sl * 20];
#pragma unroll
            for (int j = 0; j < 4; j++) {
                f32x4 x = *(const f32x4*)(vrow + j * 4);
                ca[4 * j + 0] = fmaf(a, x[0], ca[4 * j + 0]);
                ca[4 * j + 1] = fmaf(a, x[1], ca[4 * j + 1]);
                ca[4 * j + 2] = fmaf(a, x[2], ca[4 * j + 2]);
                ca[4 * j + 3] = fmaf(a, x[3], ca[4 * j + 3]);
            }
        }
    }
    const float zi = zinv[t_loc];
    unsigned short* co = cbuf + ((size_t)tg * 64 + b) * 512 + sl * 16;
#pragma unroll
    for (int j = 0; j < 4; j++) {
        s16x4 o;
        o[0] = (short)f2bf(ca[4 * j + 0] * zi);
        o[1] = (short)f2bf(ca[4 * j + 1] * zi);
        o[2] = (short)f2bf(ca[4 * j + 2] * zi);
        o[3] = (short)f2bf(ca[4 * j + 3] * zi);
        *(s16x4*)(co + j * 4) = o;
    }
}

// ---------------------------------------------------------------------------
// rec_k v11 (r14-proven, unchanged)
// ---------------------------------------------------------------------------
__global__ __launch_bounds__(256, 1)
void rec_k(const unsigned short* __restrict__ Gi,
           const float* __restrict__ Whh, const float* __restrict__ bhh,
           const float* __restrict__ h0,
           unsigned int* __restrict__ hb32,
           unsigned int* __restrict__ bar,
           float* __restrict__ hs)
{
    const int tid = threadIdx.x;
    const int g = blockIdx.x >> 3;
    const int sub = blockIdx.x & 7;
    const int w = tid >> 6;
    const int lane = tid & 63;
    const int l15 = lane & 15, l4 = lane >> 4;
    const int b  = g * 8 + (l15 & 7);
    const int jb = sub * 64 + w * 16;
    const int jrow = l4 * 4;
    const bool writer = (l15 < 8);

    s16x8 wf[3][16];
#pragma unroll
    for (int gg = 0; gg < 3; gg++) {
        const float* wr = Whh + (size_t)(gg * 512 + jb + l15) * 512 + l4 * 8;
#pragma unroll
        for (int c = 0; c < 16; c++) {
            f32x4 x = *(const f32x4*)(wr + c * 32);
            f32x4 y = *(const f32x4*)(wr + c * 32 + 4);
            wf[gg][c] = pack8(x, y);
        }
    }

    float bh_r[4], bh_z[4], bh_n[4];
#pragma unroll
    for (int i = 0; i < 4; i++) {
        bh_r[i] = bhh[jb + jrow + i];
        bh_z[i] = bhh[512 + jb + jrow + i];
        bh_n[i] = bhh[1024 + jb + jrow + i];
    }
    float hp[4];
#pragma unroll
    for (int i = 0; i < 4; i++) hp[i] = h0[(size_t)b * 512 + jb + jrow + i];

    unsigned* barA = bar + g * 512;

    s16x4 g0, g1, g2;
    {
        const unsigned short* gp = Gi + (size_t)b * 1536 + jb + jrow;
        g0 = *(const s16x4*)(gp);
        g1 = *(const s16x4*)(gp + 512);
        g2 = *(const s16x4*)(gp + 1024);
    }

#define LDH(i, lit) asm volatile("global_load_dwordx4 %0, %1, off offset:" lit " sc1" \
                                 : "=v"(hfrag2[i]) : "v"(src) : "memory");

    for (int t = 0; t < 512; t++) {
        s16x8 hfrag[16];
        if (t == 0) {
            const float* hr = h0 + (size_t)b * 512 + l4 * 8;
#pragma unroll
            for (int c = 0; c < 16; c++) {
                f32x4 x = *(const f32x4*)(hr + c * 32);
                f32x4 y = *(const f32x4*)(hr + c * 32 + 4);
                hfrag[c] = pack8(x, y);
            }
        } else {
            const unsigned int* src = hb32 + (t & 1) * 16384 + b * 256 + l4 * 4;
            s16x8 hfrag2[16];
            LDH(0, "0")   LDH(1, "64")  LDH(2, "128")  LDH(3, "192")
            LDH(4, "256") LDH(5, "320") LDH(6, "384")  LDH(7, "448")
            LDH(8, "512") LDH(9, "576") LDH(10, "640") LDH(11, "704")
            LDH(12, "768") LDH(13, "832") LDH(14, "896") LDH(15, "960")
            vm_drain();
            __builtin_amdgcn_sched_barrier(0);
#pragma unroll
            for (int c = 0; c < 16; c++) hfrag[c] = hfrag2[c];
        }

        f32x4 acc0 = {0.f, 0.f, 0.f, 0.f};
        f32x4 acc1 = {0.f, 0.f, 0.f, 0.f};
        f32x4 acc2 = {0.f, 0.f, 0.f, 0.f};
#pragma unroll
        for (int c = 0; c < 16; c++) {
            acc0 = mfma16(wf[0][c], hfrag[c], acc0);
            acc1 = mfma16(wf[1][c], hfrag[c], acc1);
            acc2 = mfma16(wf[2][c], hfrag[c], acc2);
        }

#pragma unroll
        for (int i = 0; i < 4; i++) {
            float rr = sigmoid_fast(bf2f((unsigned short)g0[i]) + acc0[i] + bh_r[i]);
            float zz = sigmoid_fast(bf2f((unsigned short)g1[i]) + acc1[i] + bh_z[i]);
            float nn = tanh_fast(bf2f((unsigned short)g2[i]) + rr * (acc2[i] + bh_n[i]));
            hp[i] = fmaf(zz, hp[i] - nn, nn);
        }

        float* hso = hs + ((size_t)t * 64 + b) * 512 + jb + jrow;
        f32x4 hv = {hp[0], hp[1], hp[2], hp[3]};

        if (t < 511) {
            if (writer) {
                u32x2 pp;
                pp[0] = (unsigned)f2bf(hp[0]) | ((unsigned)f2bf(hp[1]) << 16);
                pp[1] = (unsigned)f2bf(hp[2]) | ((unsigned)f2bf(hp[3]) << 16);
                unsigned int* dst = hb32 + ((t + 1) & 1) * 16384 + b * 256 + ((jb + jrow) >> 1);
                asm volatile("global_store_dwordx2 %0, %1, off sc1"
                             :: "v"(dst), "v"(pp) : "memory");
            }
            vm_drain();
            __syncthreads();
            if (tid == 0) add_agent(barA + t, 1u);

            if (writer) *(f32x4*)hso = hv;
            s16x4 n0, n1, n2;
            {
                const unsigned short* gp = Gi + ((size_t)(t + 1) * 64 + b) * 1536 + jb + jrow;
                n0 = *(const s16x4*)(gp);
                n1 = *(const s16x4*)(gp + 512);
                n2 = *(const s16x4*)(gp + 1024);
            }

            for (;;) {
                unsigned vb = ld_agent(barA + t);
                if (vb >= 8u) break;
                __builtin_amdgcn_s_sleep(1);
            }
            g0 = n0; g1 = n1; g2 = n2;
        } else {
            if (writer) *(f32x4*)hso = hv;
        }
    }
#undef LDH
}

// ---------------------------------------------------------------------------
// ws layout (bytes):
//   Ep : [0, 64Mi)  f32 | Eq : [64Mi, 128Mi) f32 | c : [128Mi, 160Mi) bf16
//   Gi : [0, 96Mi)  bf16 (overlays Ep/Eq, dead by then)
//   hb32 : [160Mi, +128Ki)  | bar : [160Mi+128Ki, +16Ki) (memset per launch)
// ---------------------------------------------------------------------------
extern "C" void kernel_launch(void* const* d_in, const int* in_sizes, int n_in,
                              void* d_out, int out_size, void* d_ws, size_t ws_size,
                              hipStream_t stream)
{
    (void)in_sizes; (void)n_in; (void)out_size; (void)ws_size;
    const float* v   = (const float*)d_in[0];
    const float* h0  = (const float*)d_in[1];
    const float* Vv  = (const float*)d_in[2];
    const float* Wp  = (const float*)d_in[3];
    const float* Wp_ = (const float*)d_in[4];
    const float* Wih = (const float*)d_in[5];
    const float* Whh = (const float*)d_in[6];
    const float* bih = (const float*)d_in[7];
    const float* bhh = (const float*)d_in[8];
    float* hs = (float*)d_out;

    char* ws = (char*)d_ws;
    float* Ep = (float*)(ws);
    float* Eq = (float*)(ws + 67108864ULL);
    unsigned short* cb  = (unsigned short*)(ws + 134217728ULL);
    unsigned short* Gi  = (unsigned short*)(ws);
    unsigned int*   hb32 = (unsigned int*)(ws + 167772160ULL);
    unsigned int*   bar  = (unsigned int*)(ws + 167772160ULL + 131072ULL);

    hipMemsetAsync(bar, 0, 4096 * sizeof(unsigned int), stream);

    pq_k<<<dim3(256, 4), 256, 0, stream>>>(v, Wp, Wp_, Ep, Eq);

    att_k<<<dim3(32, 64), 512, 0, stream>>>(Ep, Eq, Vv, v, cb);

    gi_k<<<dim3(256, 12), 256, 0, stream>>>(cb, Wih, bih, Gi, 1536);

    rec_k<<<dim3(64), 256, 0, stream>>>(Gi, Whh, bhh, h0, hb32, bar, hs);
}

// Round 16
// 3512.098 us; speedup vs baseline: 2.0698x; 1.0956x over previous
//
#include <hip/hip_runtime.h>
#include <hip/hip_bf16.h>

// L=512, B=64, D=H=512, 3H=1536.
//  pq_k : Ep = exp(2·v@Wp^T), Eq = exp(2·v@Wp_^T)  (split-bf16 3-pass MFMA)
//  att_s: logits (exp form, paired rcps) + softmax; writes normalized a (bf16)
//  ac_k : c[t,b,:] = a[t,b,:] @ v[:,b,:]  — 64 per-b GEMMs on MFMA
//         (v transposed to [d][l] in LDS; u32-packed transpose writes)
//  gi_k : Gi = c@W_ih^T + b_ih  (bf16)
//  rec_k: r14-proven path (sc1 h exchange, dwordx4 loads, agent flag + poll)

typedef float f32x4 __attribute__((ext_vector_type(4)));
typedef short s16x8 __attribute__((ext_vector_type(8)));
typedef short s16x4 __attribute__((ext_vector_type(4)));
typedef unsigned int u32x2 __attribute__((ext_vector_type(2)));

static __device__ __forceinline__ float rcp_fast(float x) { return __builtin_amdgcn_rcpf(x); }
static __device__ __forceinline__ float tanh_fast(float x) {
    float e = __expf(2.0f * x);
    return 1.0f - 2.0f * rcp_fast(e + 1.0f);
}
static __device__ __forceinline__ float sigmoid_fast(float x) {
    return rcp_fast(1.0f + __expf(-x));
}
static __device__ __forceinline__ unsigned short f2bf(float x) {
    union { float f; unsigned u; } v; v.f = x;
    unsigned r = v.u + 0x7FFFu + ((v.u >> 16) & 1u);
    return (unsigned short)(r >> 16);
}
static __device__ __forceinline__ float bf2f(unsigned short b) {
    union { unsigned u; float f; } v; v.u = ((unsigned)b) << 16;
    return v.f;
}
static __device__ __forceinline__ s16x8 pack8(f32x4 a, f32x4 b) {
    s16x8 r;
    r[0] = (short)f2bf(a[0]); r[1] = (short)f2bf(a[1]);
    r[2] = (short)f2bf(a[2]); r[3] = (short)f2bf(a[3]);
    r[4] = (short)f2bf(b[0]); r[5] = (short)f2bf(b[1]);
    r[6] = (short)f2bf(b[2]); r[7] = (short)f2bf(b[3]);
    return r;
}
static __device__ __forceinline__ void split8(f32x4 a, f32x4 b, s16x8* hi, s16x8* lo) {
    s16x8 h, l;
#pragma unroll
    for (int e = 0; e < 4; e++) {
        unsigned short hh = f2bf(a[e]); h[e] = (short)hh;
        l[e] = (short)f2bf(a[e] - bf2f(hh));
    }
#pragma unroll
    for (int e = 0; e < 4; e++) {
        unsigned short hh = f2bf(b[e]); h[4 + e] = (short)hh;
        l[4 + e] = (short)f2bf(b[e] - bf2f(hh));
    }
    *hi = h; *lo = l;
}
static __device__ __forceinline__ f32x4 mfma16(s16x8 a, s16x8 b, f32x4 c) {
    return __builtin_amdgcn_mfma_f32_16x16x32_bf16(a, b, c, 0, 0, 0);
}
static __device__ __forceinline__ unsigned ld_agent(const unsigned* p) {
    return __hip_atomic_load(p, __ATOMIC_RELAXED, __HIP_MEMORY_SCOPE_AGENT);
}
static __device__ __forceinline__ void add_agent(unsigned* p, unsigned v) {
    __hip_atomic_fetch_add(p, v, __ATOMIC_RELAXED, __HIP_MEMORY_SCOPE_AGENT);
}
static __device__ __forceinline__ void vm_drain() {
    asm volatile("s_waitcnt vmcnt(0)" ::: "memory");
}

// ---------------------------------------------------------------------------
// Fused P/Q GEMM (r14-proven)
// ---------------------------------------------------------------------------
__global__ __launch_bounds__(256, 2)
void pq_k(const float* __restrict__ v, const float* __restrict__ Wp,
          const float* __restrict__ Wp_, float* __restrict__ Ep,
          float* __restrict__ Eq)
{
    const int bm = blockIdx.x, bn = blockIdx.y;
    const int tid = threadIdx.x;
    const int w = tid >> 6, lane = tid & 63;
    const int l15 = lane & 15, l4 = lane >> 4;

    __shared__ unsigned short Al[128 * 72 * 2];
    __shared__ unsigned short Wl[128 * 72 * 2];
    const int LOFS = 128 * 72;

    f32x4 accP[4][4], accQ[4][4];
#pragma unroll
    for (int i = 0; i < 4; i++)
#pragma unroll
        for (int j = 0; j < 4; j++) {
            accP[i][j] = (f32x4){0.f, 0.f, 0.f, 0.f};
            accQ[i][j] = (f32x4){0.f, 0.f, 0.f, 0.f};
        }

    const int srow = tid >> 1, shalf = tid & 1;
    const float* Asrc  = v   + (size_t)(bm * 128 + srow) * 512 + shalf * 32;
    const float* W1src = Wp  + (size_t)(bn * 128 + srow) * 512 + shalf * 32;
    const float* W2src = Wp_ + (size_t)(bn * 128 + srow) * 512 + shalf * 32;
    unsigned short* Adst = Al + srow * 72 + shalf * 32;
    unsigned short* Wdst = Wl + srow * 72 + shalf * 32;

    for (int k0 = 0; k0 < 512; k0 += 64) {
        __syncthreads();
#pragma unroll
        for (int j = 0; j < 4; j++) {
            f32x4 x = *(const f32x4*)(Asrc + k0 + j * 8);
            f32x4 y = *(const f32x4*)(Asrc + k0 + j * 8 + 4);
            s16x8 hi, lo; split8(x, y, &hi, &lo);
            *(s16x8*)(Adst + j * 8) = hi;
            *(s16x8*)(Adst + LOFS + j * 8) = lo;
        }
#pragma unroll
        for (int j = 0; j < 4; j++) {
            f32x4 x = *(const f32x4*)(W1src + k0 + j * 8);
            f32x4 y = *(const f32x4*)(W1src + k0 + j * 8 + 4);
            s16x8 hi, lo; split8(x, y, &hi, &lo);
            *(s16x8*)(Wdst + j * 8) = hi;
            *(s16x8*)(Wdst + LOFS + j * 8) = lo;
        }
        __syncthreads();

#pragma unroll
        for (int kt = 0; kt < 2; kt++) {
            s16x8 afh[4], afl[4], bfh[4], bfl[4];
#pragma unroll
            for (int mb = 0; mb < 4; mb++) {
                afh[mb] = *(const s16x8*)(Al + ((w & 1) * 64 + mb * 16 + l15) * 72 + kt * 32 + l4 * 8);
                afl[mb] = *(const s16x8*)(Al + LOFS + ((w & 1) * 64 + mb * 16 + l15) * 72 + kt * 32 + l4 * 8);
            }
#pragma unroll
            for (int nb = 0; nb < 4; nb++) {
                bfh[nb] = *(const s16x8*)(Wl + ((w >> 1) * 64 + nb * 16 + l15) * 72 + kt * 32 + l4 * 8);
                bfl[nb] = *(const s16x8*)(Wl + LOFS + ((w >> 1) * 64 + nb * 16 + l15) * 72 + kt * 32 + l4 * 8);
            }
#pragma unroll
            for (int mb = 0; mb < 4; mb++)
#pragma unroll
                for (int nb = 0; nb < 4; nb++) {
                    accP[mb][nb] = mfma16(afh[mb], bfh[nb], accP[mb][nb]);
                    accP[mb][nb] = mfma16(afh[mb], bfl[nb], accP[mb][nb]);
                    accP[mb][nb] = mfma16(afl[mb], bfh[nb], accP[mb][nb]);
                }
        }

        __syncthreads();
#pragma unroll
        for (int j = 0; j < 4; j++) {
            f32x4 x = *(const f32x4*)(W2src + k0 + j * 8);
            f32x4 y = *(const f32x4*)(W2src + k0 + j * 8 + 4);
            s16x8 hi, lo; split8(x, y, &hi, &lo);
            *(s16x8*)(Wdst + j * 8) = hi;
            *(s16x8*)(Wdst + LOFS + j * 8) = lo;
        }
        __syncthreads();

#pragma unroll
        for (int kt = 0; kt < 2; kt++) {
            s16x8 afh[4], afl[4], bfh[4], bfl[4];
#pragma unroll
            for (int mb = 0; mb < 4; mb++) {
                afh[mb] = *(const s16x8*)(Al + ((w & 1) * 64 + mb * 16 + l15) * 72 + kt * 32 + l4 * 8);
                afl[mb] = *(const s16x8*)(Al + LOFS + ((w & 1) * 64 + mb * 16 + l15) * 72 + kt * 32 + l4 * 8);
            }
#pragma unroll
            for (int nb = 0; nb < 4; nb++) {
                bfh[nb] = *(const s16x8*)(Wl + ((w >> 1) * 64 + nb * 16 + l15) * 72 + kt * 32 + l4 * 8);
                bfl[nb] = *(const s16x8*)(Wl + LOFS + ((w >> 1) * 64 + nb * 16 + l15) * 72 + kt * 32 + l4 * 8);
            }
#pragma unroll
            for (int mb = 0; mb < 4; mb++)
#pragma unroll
                for (int nb = 0; nb < 4; nb++) {
                    accQ[mb][nb] = mfma16(afh[mb], bfh[nb], accQ[mb][nb]);
                    accQ[mb][nb] = mfma16(afh[mb], bfl[nb], accQ[mb][nb]);
                    accQ[mb][nb] = mfma16(afl[mb], bfh[nb], accQ[mb][nb]);
                }
        }
    }

    const int m0 = bm * 128 + (w & 1) * 64;
    const int n0 = bn * 128 + (w >> 1) * 64;
#pragma unroll
    for (int nb = 0; nb < 4; nb++) {
        const int n = n0 + nb * 16 + l15;
#pragma unroll
        for (int mb = 0; mb < 4; mb++) {
#pragma unroll
            for (int i = 0; i < 4; i++) {
                const int m = m0 + mb * 16 + l4 * 4 + i;
                Ep[(size_t)m * 512 + n] = __expf(2.0f * accP[mb][nb][i]);
                Eq[(size_t)m * 512 + n] = __expf(2.0f * accQ[mb][nb][i]);
            }
        }
    }
}

// ---------------------------------------------------------------------------
// att_s: logits + softmax only; writes normalized a (bf16) to abuf[b][t][l].
// block = (t-tile of 16, b), 512 threads.
// ---------------------------------------------------------------------------
__global__ __launch_bounds__(512, 4)
void att_s(const float* __restrict__ Ept, const float* __restrict__ Eqt,
           const float* __restrict__ Vv, unsigned short* __restrict__ abuf)
{
    const int tblk = blockIdx.x, b = blockIdx.y;
    const int tid = threadIdx.x;
    const int w = tid >> 6, lane = tid & 63;
    const int t_in = lane >> 5, sl = lane & 31;
    const int t_loc = w * 2 + t_in;          // 0..15
    const int tg = tblk * 16 + t_loc;        // global t

    __shared__ float sbuf[16][513];
    __shared__ float qst[8][640];
    __shared__ float zinv[16];

    float Ep[16], Vb2[16];
    float VbS = 0.0f;
    {
        const float* pp = Ept + ((size_t)tg * 64 + b) * 512 + sl * 16;
        const float* vb = Vv + (size_t)b * 512 + sl * 16;
#pragma unroll
        for (int j = 0; j < 4; j++) {
            f32x4 x = *(const f32x4*)(pp + j * 4);
            f32x4 y = *(const f32x4*)(vb + j * 4);
#pragma unroll
            for (int e = 0; e < 4; e++) {
                Ep[j * 4 + e] = x[e];
                Vb2[j * 4 + e] = 2.0f * y[e];
                VbS += y[e];
            }
        }
    }

    // Phase A: paired-rcp logits
    for (int l0 = 0; l0 < 512; l0 += 8) {
        __syncthreads();
        {
            const int row = tid >> 6;
            const int cb = (tid & 63) * 8;
            const float* src = Eqt + ((size_t)(l0 + row) * 64 + b) * 512 + cb;
            const int f0 = cb + 4 * (cb >> 4);
            *(f32x4*)(&qst[row][f0])     = *(const f32x4*)(src);
            *(f32x4*)(&qst[row][f0 + 4]) = *(const f32x4*)(src + 4);
        }
        __syncthreads();
        for (int l = 0; l < 8; l++) {
            const float* qrow = &qst[l][sl * 20];
            float a0 = VbS, a1 = 0.f;
#pragma unroll
            for (int j = 0; j < 4; j++) {
                f32x4 q = *(const f32x4*)(qrow + j * 4);
                float d0 = fmaf(Ep[4 * j + 0], q[0], 1.0f);
                float d1 = fmaf(Ep[4 * j + 1], q[1], 1.0f);
                float d2 = fmaf(Ep[4 * j + 2], q[2], 1.0f);
                float d3 = fmaf(Ep[4 * j + 3], q[3], 1.0f);
                float m01 = d0 * d1;
                float m23 = d2 * d3;
                float n01 = Vb2[4 * j + 0] * d1;
                n01 = fmaf(Vb2[4 * j + 1], d0, n01);
                float n23 = Vb2[4 * j + 2] * d3;
                n23 = fmaf(Vb2[4 * j + 3], d2, n23);
                a0 = fmaf(-n01, rcp_fast(m01), a0);
                a1 = fmaf(-n23, rcp_fast(m23), a1);
            }
            float accp = a0 + a1;
#pragma unroll
            for (int m = 1; m < 32; m <<= 1) accp += __shfl_xor(accp, m, 64);
            if (sl == 0) sbuf[t_loc][l0 + l] = accp;
        }
    }
    __syncthreads();

    // Phase B: softmax (unnormalized exp + 1/Z)
    {
        const int tr = tid >> 5;
        const int i = tid & 31;
        float m = -1e30f;
        for (int l = i; l < 512; l += 32) m = fmaxf(m, sbuf[tr][l]);
#pragma unroll
        for (int mm = 1; mm < 32; mm <<= 1) m = fmaxf(m, __shfl_xor(m, mm, 64));
        float z = 0.0f;
        for (int l = i; l < 512; l += 32) {
            float e = __expf(sbuf[tr][l] - m);
            sbuf[tr][l] = e;
            z += e;
        }
#pragma unroll
        for (int mm = 1; mm < 32; mm <<= 1) z += __shfl_xor(z, mm, 64);
        if (i == 0) zinv[tr] = rcp_fast(z);
    }
    __syncthreads();

    // write normalized a (bf16) to abuf[b][t][l]; lane i owns l = i*16..+16
    {
        const int tr = tid >> 5;
        const int i = tid & 31;
        const float zi = zinv[tr];
        const int tg2 = tblk * 16 + tr;
        unsigned short* dst = abuf + ((size_t)b * 512 + tg2) * 512 + i * 16;
        s16x8 o0, o1;
#pragma unroll
        for (int e = 0; e < 8; e++) o0[e] = (short)f2bf(sbuf[tr][i * 16 + e] * zi);
#pragma unroll
        for (int e = 0; e < 8; e++) o1[e] = (short)f2bf(sbuf[tr][i * 16 + 8 + e] * zi);
        *(s16x8*)(dst)     = o0;
        *(s16x8*)(dst + 8) = o1;
    }
}

// ---------------------------------------------------------------------------
// ac_k: per-b GEMM  c[t][d] = Σ_l a[t][l]·v[l][d].
// grid (4 t-tiles, 4 d-tiles, 64 b), 256 threads, 128x128 tile, BK=64.
// v transposed to LDS [d][l] (stride 72) with u32-packed writes.
// ---------------------------------------------------------------------------
__global__ __launch_bounds__(256, 2)
void ac_k(const unsigned short* __restrict__ abuf,  // [b][t][l] bf16
          const float* __restrict__ vin,            // [l][b][d] f32
          unsigned short* __restrict__ cbuf)        // [(t*64+b)][d] bf16
{
    const int bt = blockIdx.x, bd = blockIdx.y, b = blockIdx.z;
    const int tid = threadIdx.x;
    const int w = tid >> 6, lane = tid & 63;
    const int l15 = lane & 15, l4 = lane >> 4;

    __shared__ unsigned short Al[128 * 72];
    __shared__ unsigned short Wt[128 * 72];   // [d_local][l_local], stride 72

    f32x4 acc[4][4];
#pragma unroll
    for (int i = 0; i < 4; i++)
#pragma unroll
        for (int j = 0; j < 4; j++) acc[i][j] = (f32x4){0.f, 0.f, 0.f, 0.f};

    const int srow = tid >> 1, shalf = tid & 1;
    const unsigned short* Asrc = abuf + ((size_t)b * 512 + bt * 128 + srow) * 512 + shalf * 32;
    unsigned short* Adst = Al + srow * 72 + shalf * 32;

    const int lpair = tid & 31;          // l rows 2*lpair, 2*lpair+1
    const int dgrp  = tid >> 5;          // 0..7, 16 d's each

    for (int k0 = 0; k0 < 512; k0 += 64) {
        __syncthreads();
#pragma unroll
        for (int j = 0; j < 4; j++)
            *(s16x8*)(Adst + j * 8) = *(const s16x8*)(Asrc + k0 + j * 8);
        {
            const float* r0 = vin + ((size_t)(k0 + 2 * lpair) * 64 + b) * 512 + bd * 128 + dgrp * 16;
            const float* r1 = r0 + 64 * 512;
            f32x4 x0[4], x1[4];
#pragma unroll
            for (int j = 0; j < 4; j++) {
                x0[j] = *(const f32x4*)(r0 + j * 4);
                x1[j] = *(const f32x4*)(r1 + j * 4);
            }
            unsigned* wt32 = (unsigned*)Wt;
#pragma unroll
            for (int j = 0; j < 4; j++)
#pragma unroll
                for (int e = 0; e < 4; e++) {
                    const int d = dgrp * 16 + j * 4 + e;
                    wt32[d * 36 + lpair] =
                        (unsigned)f2bf(x0[j][e]) | ((unsigned)f2bf(x1[j][e]) << 16);
                }
        }
        __syncthreads();

#pragma unroll
        for (int kt = 0; kt < 2; kt++) {
            s16x8 afh[4], bfh[4];
#pragma unroll
            for (int mb = 0; mb < 4; mb++)
                afh[mb] = *(const s16x8*)(Al + ((w & 1) * 64 + mb * 16 + l15) * 72 + kt * 32 + l4 * 8);
#pragma unroll
            for (int nb = 0; nb < 4; nb++)
                bfh[nb] = *(const s16x8*)(Wt + ((w >> 1) * 64 + nb * 16 + l15) * 72 + kt * 32 + l4 * 8);
#pragma unroll
            for (int mb = 0; mb < 4; mb++)
#pragma unroll
                for (int nb = 0; nb < 4; nb++)
                    acc[mb][nb] = mfma16(afh[mb], bfh[nb], acc[mb][nb]);
        }
    }

    const int t0 = bt * 128 + (w & 1) * 64;
    const int d0 = bd * 128 + (w >> 1) * 64;
#pragma unroll
    for (int nb = 0; nb < 4; nb++) {
        const int d = d0 + nb * 16 + l15;
#pragma unroll
        for (int mb = 0; mb < 4; mb++) {
#pragma unroll
            for (int i = 0; i < 4; i++) {
                const int t = t0 + mb * 16 + l4 * 4 + i;
                cbuf[((size_t)t * 64 + b) * 512 + d] = f2bf(acc[mb][nb][i]);
            }
        }
    }
}

// ---------------------------------------------------------------------------
// Gi GEMM (r14-proven)
// ---------------------------------------------------------------------------
__global__ __launch_bounds__(256, 2)
void gi_k(const unsigned short* __restrict__ Ap, const float* __restrict__ Wp,
          const float* __restrict__ bias, unsigned short* __restrict__ outp, int N)
{
    const int bm = blockIdx.x, bn = blockIdx.y;
    const int tid = threadIdx.x;
    const int w = tid >> 6, lane = tid & 63;
    const int l15 = lane & 15, l4 = lane >> 4;

    __shared__ unsigned short Al[128 * 72];
    __shared__ unsigned short Wl[128 * 72];

    f32x4 acc[4][4];
#pragma unroll
    for (int i = 0; i < 4; i++)
#pragma unroll
        for (int j = 0; j < 4; j++) acc[i][j] = (f32x4){0.f, 0.f, 0.f, 0.f};

    const int srow = tid >> 1, shalf = tid & 1;
    const unsigned short* Asrcb = Ap + (size_t)(bm * 128 + srow) * 512 + shalf * 32;
    const float* Wsrc = Wp + (size_t)(bn * 128 + srow) * 512 + shalf * 32;
    unsigned short* Adst = Al + srow * 72 + shalf * 32;
    unsigned short* Wdst = Wl + srow * 72 + shalf * 32;

    for (int k0 = 0; k0 < 512; k0 += 64) {
        __syncthreads();
#pragma unroll
        for (int j = 0; j < 4; j++)
            *(s16x8*)(Adst + j * 8) = *(const s16x8*)(Asrcb + k0 + j * 8);
#pragma unroll
        for (int j = 0; j < 4; j++) {
            f32x4 x = *(const f32x4*)(Wsrc + k0 + j * 8);
            f32x4 y = *(const f32x4*)(Wsrc + k0 + j * 8 + 4);
            *(s16x8*)(Wdst + j * 8) = pack8(x, y);
        }
        __syncthreads();

#pragma unroll
        for (int kt = 0; kt < 2; kt++) {
            s16x8 afh[4], bfh[4];
#pragma unroll
            for (int mb = 0; mb < 4; mb++)
                afh[mb] = *(const s16x8*)(Al + ((w & 1) * 64 + mb * 16 + l15) * 72 + kt * 32 + l4 * 8);
#pragma unroll
            for (int nb = 0; nb < 4; nb++)
                bfh[nb] = *(const s16x8*)(Wl + ((w >> 1) * 64 + nb * 16 + l15) * 72 + kt * 32 + l4 * 8);
#pragma unroll
            for (int mb = 0; mb < 4; mb++)
#pragma unroll
                for (int nb = 0; nb < 4; nb++)
                    acc[mb][nb] = mfma16(afh[mb], bfh[nb], acc[mb][nb]);
        }
    }

    const int m0 = bm * 128 + (w & 1) * 64;
    const int n0 = bn * 128 + (w >> 1) * 64;
#pragma unroll
    for (int nb = 0; nb < 4; nb++) {
        const int n = n0 + nb * 16 + l15;
        const float bv = bias[n];
#pragma unroll
        for (int mb = 0; mb < 4; mb++) {
#pragma unroll
            for (int i = 0; i < 4; i++) {
                const int m = m0 + mb * 16 + l4 * 4 + i;
                outp[(size_t)m * N + n] = f2bf(acc[mb][nb][i] + bv);
            }
        }
    }
}

// ---------------------------------------------------------------------------
// rec_k v11 (r14-proven, unchanged)
// ---------------------------------------------------------------------------
__global__ __launch_bounds__(256, 1)
void rec_k(const unsigned short* __restrict__ Gi,
           const float* __restrict__ Whh, const float* __restrict__ bhh,
           const float* __restrict__ h0,
           unsigned int* __restrict__ hb32,
           unsigned int* __restrict__ bar,
           float* __restrict__ hs)
{
    const int tid = threadIdx.x;
    const int g = blockIdx.x >> 3;
    const int sub = blockIdx.x & 7;
    const int w = tid >> 6;
    const int lane = tid & 63;
    const int l15 = lane & 15, l4 = lane >> 4;
    const int b  = g * 8 + (l15 & 7);
    const int jb = sub * 64 + w * 16;
    const int jrow = l4 * 4;
    const bool writer = (l15 < 8);

    s16x8 wf[3][16];
#pragma unroll
    for (int gg = 0; gg < 3; gg++) {
        const float* wr = Whh + (size_t)(gg * 512 + jb + l15) * 512 + l4 * 8;
#pragma unroll
        for (int c = 0; c < 16; c++) {
            f32x4 x = *(const f32x4*)(wr + c * 32);
            f32x4 y = *(const f32x4*)(wr + c * 32 + 4);
            wf[gg][c] = pack8(x, y);
        }
    }

    float bh_r[4], bh_z[4], bh_n[4];
#pragma unroll
    for (int i = 0; i < 4; i++) {
        bh_r[i] = bhh[jb + jrow + i];
        bh_z[i] = bhh[512 + jb + jrow + i];
        bh_n[i] = bhh[1024 + jb + jrow + i];
    }
    float hp[4];
#pragma unroll
    for (int i = 0; i < 4; i++) hp[i] = h0[(size_t)b * 512 + jb + jrow + i];

    unsigned* barA = bar + g * 512;

    s16x4 g0, g1, g2;
    {
        const unsigned short* gp = Gi + (size_t)b * 1536 + jb + jrow;
        g0 = *(const s16x4*)(gp);
        g1 = *(const s16x4*)(gp + 512);
        g2 = *(const s16x4*)(gp + 1024);
    }

#define LDH(i, lit) asm volatile("global_load_dwordx4 %0, %1, off offset:" lit " sc1" \
                                 : "=v"(hfrag2[i]) : "v"(src) : "memory");

    for (int t = 0; t < 512; t++) {
        s16x8 hfrag[16];
        if (t == 0) {
            const float* hr = h0 + (size_t)b * 512 + l4 * 8;
#pragma unroll
            for (int c = 0; c < 16; c++) {
                f32x4 x = *(const f32x4*)(hr + c * 32);
                f32x4 y = *(const f32x4*)(hr + c * 32 + 4);
                hfrag[c] = pack8(x, y);
            }
        } else {
            const unsigned int* src = hb32 + (t & 1) * 16384 + b * 256 + l4 * 4;
            s16x8 hfrag2[16];
            LDH(0, "0")   LDH(1, "64")  LDH(2, "128")  LDH(3, "192")
            LDH(4, "256") LDH(5, "320") LDH(6, "384")  LDH(7, "448")
            LDH(8, "512") LDH(9, "576") LDH(10, "640") LDH(11, "704")
            LDH(12, "768") LDH(13, "832") LDH(14, "896") LDH(15, "960")
            vm_drain();
            __builtin_amdgcn_sched_barrier(0);
#pragma unroll
            for (int c = 0; c < 16; c++) hfrag[c] = hfrag2[c];
        }

        f32x4 acc0 = {0.f, 0.f, 0.f, 0.f};
        f32x4 acc1 = {0.f, 0.f, 0.f, 0.f};
        f32x4 acc2 = {0.f, 0.f, 0.f, 0.f};
#pragma unroll
        for (int c = 0; c < 16; c++) {
            acc0 = mfma16(wf[0][c], hfrag[c], acc0);
            acc1 = mfma16(wf[1][c], hfrag[c], acc1);
            acc2 = mfma16(wf[2][c], hfrag[c], acc2);
        }

#pragma unroll
        for (int i = 0; i < 4; i++) {
            float rr = sigmoid_fast(bf2f((unsigned short)g0[i]) + acc0[i] + bh_r[i]);
            float zz = sigmoid_fast(bf2f((unsigned short)g1[i]) + acc1[i] + bh_z[i]);
            float nn = tanh_fast(bf2f((unsigned short)g2[i]) + rr * (acc2[i] + bh_n[i]));
            hp[i] = fmaf(zz, hp[i] - nn, nn);
        }

        float* hso = hs + ((size_t)t * 64 + b) * 512 + jb + jrow;
        f32x4 hv = {hp[0], hp[1], hp[2], hp[3]};

        if (t < 511) {
            if (writer) {
                u32x2 pp;
                pp[0] = (unsigned)f2bf(hp[0]) | ((unsigned)f2bf(hp[1]) << 16);
                pp[1] = (unsigned)f2bf(hp[2]) | ((unsigned)f2bf(hp[3]) << 16);
                unsigned int* dst = hb32 + ((t + 1) & 1) * 16384 + b * 256 + ((jb + jrow) >> 1);
                asm volatile("global_store_dwordx2 %0, %1, off sc1"
                             :: "v"(dst), "v"(pp) : "memory");
            }
            vm_drain();
            __syncthreads();
            if (tid == 0) add_agent(barA + t, 1u);

            if (writer) *(f32x4*)hso = hv;
            s16x4 n0, n1, n2;
            {
                const unsigned short* gp = Gi + ((size_t)(t + 1) * 64 + b) * 1536 + jb + jrow;
                n0 = *(const s16x4*)(gp);
                n1 = *(const s16x4*)(gp + 512);
                n2 = *(const s16x4*)(gp + 1024);
            }

            for (;;) {
                unsigned vb = ld_agent(barA + t);
                if (vb >= 8u) break;
                __builtin_amdgcn_s_sleep(1);
            }
            g0 = n0; g1 = n1; g2 = n2;
        } else {
            if (writer) *(f32x4*)hso = hv;
        }
    }
#undef LDH
}

// ---------------------------------------------------------------------------
// ws layout (bytes):
//   Ep   : [0, 64Mi)     f32
//   Eq   : [64Mi, 128Mi) f32
//   abuf : [128Mi, 160Mi) bf16  a[b][t][l]
//   c    : [160Mi, 192Mi) bf16
//   Gi   : [0, 96Mi)     bf16 (overlays Ep/Eq/abuf — all dead after ac_k)
//   hb32 : [192Mi, +128Ki) | bar : next 16Ki (memset per launch)
// total ~192.3 MiB (r1-proven footprint)
// ---------------------------------------------------------------------------
extern "C" void kernel_launch(void* const* d_in, const int* in_sizes, int n_in,
                              void* d_out, int out_size, void* d_ws, size_t ws_size,
                              hipStream_t stream)
{
    (void)in_sizes; (void)n_in; (void)out_size; (void)ws_size;
    const float* v   = (const float*)d_in[0];
    const float* h0  = (const float*)d_in[1];
    const float* Vv  = (const float*)d_in[2];
    const float* Wp  = (const float*)d_in[3];
    const float* Wp_ = (const float*)d_in[4];
    const float* Wih = (const float*)d_in[5];
    const float* Whh = (const float*)d_in[6];
    const float* bih = (const float*)d_in[7];
    const float* bhh = (const float*)d_in[8];
    float* hs = (float*)d_out;

    char* ws = (char*)d_ws;
    float* Ep = (float*)(ws);
    float* Eq = (float*)(ws + 67108864ULL);
    unsigned short* abuf = (unsigned short*)(ws + 134217728ULL);
    unsigned short* cb   = (unsigned short*)(ws + 167772160ULL);
    unsigned short* Gi   = (unsigned short*)(ws);
    unsigned int*   hb32 = (unsigned int*)(ws + 201326592ULL);
    unsigned int*   bar  = (unsigned int*)(ws + 201326592ULL + 131072ULL);

    hipMemsetAsync(bar, 0, 4096 * sizeof(unsigned int), stream);

    pq_k<<<dim3(256, 4), 256, 0, stream>>>(v, Wp, Wp_, Ep, Eq);

    att_s<<<dim3(32, 64), 512, 0, stream>>>(Ep, Eq, Vv, abuf);

    ac_k<<<dim3(4, 4, 64), 256, 0, stream>>>(abuf, v, cb);

    gi_k<<<dim3(256, 12), 256, 0, stream>>>(cb, Wih, bih, Gi, 1536);

    rec_k<<<dim3(64), 256, 0, stream>>>(Gi, Whh, bhh, h0, hb32, bar, hs);
}